// Round 13
// baseline (125.745 us; speedup 1.0000x reference)
//
#include <hip/hip_runtime.h>
#include <math.h>

#define NB 4
#define LQ 2048
#define DM 256
#define HH 6
#define DH 64
#define LIN 16464
#define NOA 512             // fused off(324)+attn(162) padded
#define NVAL 384

typedef unsigned short ushort_t;
typedef unsigned int uint_t;
typedef __attribute__((ext_vector_type(8))) short s8v;   // 8 bf16 = 4 VGPR
typedef __attribute__((ext_vector_type(4))) float f4v;   // MFMA accumulator

__device__ __forceinline__ ushort_t f2bf(float f) {
  union { float f; unsigned u; } v; v.f = f;
  unsigned r = v.u + 0x7fffu + ((v.u >> 16) & 1u);  // RNE
  return (ushort_t)(r >> 16);
}

__device__ __forceinline__ uint_t cvtpk(float lo, float hi) {
  uint_t r;
  asm("v_cvt_pk_bf16_f32 %0, %1, %2" : "=v"(r) : "v"(lo), "v"(hi));
  return r;
}

typedef __attribute__((address_space(3))) char lds_char_t;
typedef const __attribute__((address_space(1))) char glb_char_t;
__device__ __forceinline__ void gload16(const void* g, void* l) {
  __builtin_amdgcn_global_load_lds((glb_char_t*)g, (lds_char_t*)l, 16, 0, 0);
}

// ---------------- fused prep: addq + weight transposes + bias ----------------
__global__ __launch_bounds__(256)
void prep_k(const float4* __restrict__ tgt, const float4* __restrict__ qpos,
            ushort4* __restrict__ q_bf,
            const float* __restrict__ W_val, ushort_t* __restrict__ bt_val,
            const float* __restrict__ W_off, const float* __restrict__ W_attn,
            ushort_t* __restrict__ bt_oa,
            const float* __restrict__ W_out, ushort_t* __restrict__ bt_out,
            const float* __restrict__ b_off, const float* __restrict__ b_attn,
            float* __restrict__ bias_oa) {
  const int blk = blockIdx.x, tid = threadIdx.x;
  if (blk < 2048) {
    const int i = blk * 256 + tid;
    float4 x = tgt[i], y = qpos[i];
    ushort4 r;
    r.x = f2bf(x.x + y.x); r.y = f2bf(x.y + y.y);
    r.z = f2bf(x.z + y.z); r.w = f2bf(x.w + y.w);
    q_bf[i] = r;
  } else {
    const int i = (blk - 2048) * 256 + tid;
    if (i < 98304) {              // bt_val[n][k] = W_val[k][n], 384x256
      const int n = i >> 8, k = i & 255;
      bt_val[i] = f2bf(W_val[(size_t)k * 384 + n]);
    } else if (i < 229376) {      // bt_oa: 512x256
      const int j = i - 98304;
      const int n = j >> 8, k = j & 255;
      float v = 0.f;
      if (n < 324) v = W_off[(size_t)k * 324 + n];
      else if (n < 486) v = W_attn[(size_t)k * 162 + (n - 324)];
      bt_oa[j] = f2bf(v);
    } else if (i < 327680) {      // bt_out: 256x384
      const int j = i - 229376;
      const int n = j / 384, k = j - n * 384;
      bt_out[j] = f2bf(W_out[(size_t)k * 256 + n]);
    } else {                      // bias_oa 512
      const int j = i - 327680;
      if (j < 512) bias_oa[j] = (j < 324) ? b_off[j] : (j < 486 ? b_attn[j - 324] : 0.f);
    }
  }
}

// ------------- value GEMM: W-in-registers, barrier-free K-loop -------------
// Block = 64 global act rows (chunk) x 128 channels (4 waves x 32 ch). Wave holds its
// 32-ch x K=256 W panel in 64 VGPR (16x s8v, loaded per-lane from L2-resident bt_val).
// Acts: 16x float4 fp32 loads -> cvt_pk -> 8x LINEAR ds_write_b128 (16B/thread/kstep,
// 0 conflicts; octet swizzle oA = sA ^ ((tr&15)>>1&3), reader slot kg^rsw, R10-proven).
// ONE __syncthreads per block; then 8 ksteps x (4 ds_read_b128 + 8 MFMA) with no syncs
// (compiler inserts fine-grained lgkmcnt). Rows are GLOBAL (65856 = 1029*64 exactly,
// no padding); batch split via int-div only in the epilogue.
// Grid: 1029 chunks x 3 ch-tiles, cc fastest (3 sharers of a src chunk co-dispatch; LLC
// memory-side -> src fetched from HBM once).
__global__ __launch_bounds__(256)
void mfma_gemm_vsrc_k(const float* __restrict__ Src, const ushort_t* __restrict__ Wt,
                      const float* __restrict__ bias, ushort_t* __restrict__ Cout) {
  __shared__ char alds[8][4096];   // [kstep][64 rows][4 slots x 16B]
  const int bid = blockIdx.x;
  const int chunk = bid / 3, cc = bid - chunk * 3;
  const int g0 = chunk * 64;

  const int t = threadIdx.x;
  const int lane = t & 63, w = t >> 6;
  const int l15 = lane & 15, kg = lane >> 4;
  const int rsw = (l15 >> 1) & 3;

  // ---- act staging geometry: thread t -> row tr (0..63), slot sA, source octet oA ----
  const int tr = t >> 2, sA = t & 3;
  const int oA = sA ^ (((tr & 15) >> 1) & 3);
  const float* pa = Src + (size_t)(g0 + tr) * DM + oA * 8;

  // ---- issue act loads (16 float4 = full row-slot across 8 ksteps) ----
  float4 lf[16];
#pragma unroll
  for (int ks = 0; ks < 8; ++ks) {
    lf[2 * ks]     = *(const float4*)(pa + ks * 32);
    lf[2 * ks + 1] = *(const float4*)(pa + ks * 32 + 4);
  }

  // ---- W panel to registers: wv[mr][ks] = W[ch][ks*32 + kg*8 .. +8] ----
  const ushort_t* wp = Wt + (size_t)(cc * 128 + w * 32 + l15) * DM + kg * 8;
  s8v wv[2][8];
#pragma unroll
  for (int mr = 0; mr < 2; ++mr)
#pragma unroll
    for (int ks = 0; ks < 8; ++ks)
      wv[mr][ks] = *(const s8v*)(wp + mr * 16 * DM + ks * 32);

  // ---- cvt + LDS write (compiler inserts the vm waits before lf use) ----
#pragma unroll
  for (int ks = 0; ks < 8; ++ks) {
    uint4 c;
    c.x = cvtpk(lf[2 * ks].x, lf[2 * ks].y);
    c.y = cvtpk(lf[2 * ks].z, lf[2 * ks].w);
    c.z = cvtpk(lf[2 * ks + 1].x, lf[2 * ks + 1].y);
    c.w = cvtpk(lf[2 * ks + 1].z, lf[2 * ks + 1].w);
    *(uint4*)(&alds[ks][t * 16]) = c;
  }
  __syncthreads();    // single barrier: acts visible; W regs also drained here

  f4v acc[2][4];
#pragma unroll
  for (int i = 0; i < 2; ++i)
#pragma unroll
    for (int j = 0; j < 4; ++j) acc[i][j] = (f4v){0.f, 0.f, 0.f, 0.f};

  // ---- barrier-free K-loop: 8 ksteps x (4 ds_read_b128 + 8 MFMA) ----
#pragma unroll
  for (int ks = 0; ks < 8; ++ks) {
    s8v bv[4];
#pragma unroll
    for (int nr = 0; nr < 4; ++nr)
      bv[nr] = *(const s8v*)(&alds[ks][(nr * 16 + l15) * 64 + ((kg ^ rsw) << 4)]);
#pragma unroll
    for (int mr = 0; mr < 2; ++mr)
#pragma unroll
      for (int nr = 0; nr < 4; ++nr)
        acc[mr][nr] = __builtin_amdgcn_mfma_f32_16x16x32_bf16(wv[mr][ks], bv[nr],
                                                              acc[mr][nr], 0, 0, 0);
  }

  // ---- epilogue: ch = cc*128 + w*32 + mr*16 + kg*4 (4 contiguous), row = global g ----
#pragma unroll
  for (int mr = 0; mr < 2; ++mr) {
    const int ch = cc * 128 + w * 32 + mr * 16 + kg * 4;
    const int h = ch >> 6, dd = ch & 63;
    const float4 b4 = *(const float4*)(bias + ch);
#pragma unroll
    for (int nr = 0; nr < 4; ++nr) {
      const int g = g0 + nr * 16 + l15;
      const int bq = g / LIN;
      const int ii = g - bq * LIN;
      ushort4 o;
      o.x = f2bf(acc[mr][nr][0] + b4.x);
      o.y = f2bf(acc[mr][nr][1] + b4.y);
      o.z = f2bf(acc[mr][nr][2] + b4.z);
      o.w = f2bf(acc[mr][nr][3] + b4.w);
      *(ushort4*)(Cout + ((size_t)(bq * HH + h) * LIN + ii) * DH + dd) = o;
    }
  }
}

// ------------- bf16 MFMA GEMM (R7-proven), swapped operands, 128x128, 3-buf -------------
template <int NBX, int NBY, int CPX>
__global__ __launch_bounds__(256)
void mfma_gemm_k(const ushort_t* __restrict__ Act, const ushort_t* __restrict__ Wt,
                 const float* __restrict__ bias, float* __restrict__ Cout,
                 int N, int K) {
  __shared__ char lds[3][16384];
  const int bid = blockIdx.x;
  const int r = (bid & 7) * CPX + (bid >> 3);
  if (r >= NBX * NBY) return;
  const int bx = r / NBY, by = r - bx * NBY;
  const int m0 = bx * 128, n0 = by * 128;

  const int t = threadIdx.x;
  const int lane = t & 63, wid = t >> 6;
  const int wr = wid >> 1, wc = wid & 1;
  const int l15 = lane & 15, kg = lane >> 4;
  const int nk = K >> 5;

  const int srow = lane >> 2;
  const int koct = (lane & 3) ^ ((lane >> 3) & 3);
  const int rsw = (l15 >> 1) & 3;

  const size_t WA0 = (size_t)(n0 + wid * 16 + srow) * K + koct * 8;
  const size_t WA1 = WA0 + (size_t)64 * K;
  const size_t XB0 = (size_t)(m0 + wid * 16 + srow) * K + koct * 8;
  const size_t XB1 = XB0 + (size_t)64 * K;

  f4v acc[4][4];
#pragma unroll
  for (int i = 0; i < 4; ++i)
#pragma unroll
    for (int j = 0; j < 4; ++j) acc[i][j] = (f4v){0.f, 0.f, 0.f, 0.f};

#define STAGE(ks_)                                                       \
  { char* d_ = &lds[(ks_) % 3][0]; const int ko_ = (ks_) << 5;           \
    gload16(Wt + WA0 + ko_,  d_ + wid * 1024);                           \
    gload16(Wt + WA1 + ko_,  d_ + 4096 + wid * 1024);                    \
    gload16(Act + XB0 + ko_, d_ + 8192 + wid * 1024);                    \
    gload16(Act + XB1 + ko_, d_ + 12288 + wid * 1024); }

  STAGE(0);
  STAGE(1);

  for (int ks = 0; ks < nk; ++ks) {
    if (ks + 1 < nk) {
      asm volatile("s_waitcnt vmcnt(4)" ::: "memory");
    } else {
      asm volatile("s_waitcnt vmcnt(0)" ::: "memory");
    }
    __builtin_amdgcn_s_barrier();
    asm volatile("" ::: "memory");
    if (ks + 2 < nk) STAGE(ks + 2);

    const char* d = &lds[ks % 3][0];
    s8v av[4], bv[4];
#pragma unroll
    for (int mr = 0; mr < 4; ++mr)
      av[mr] = *(const s8v*)(d + (wr * 64 + mr * 16 + l15) * 64 + ((kg ^ rsw) << 4));
#pragma unroll
    for (int nr = 0; nr < 4; ++nr)
      bv[nr] = *(const s8v*)(d + 8192 + (wc * 64 + nr * 16 + l15) * 64 + ((kg ^ rsw) << 4));
#pragma unroll
    for (int mr = 0; mr < 4; ++mr)
#pragma unroll
      for (int nr = 0; nr < 4; ++nr)
        acc[mr][nr] = __builtin_amdgcn_mfma_f32_16x16x32_bf16(av[mr], bv[nr],
                                                              acc[mr][nr], 0, 0, 0);
  }
#undef STAGE

#pragma unroll
  for (int mr = 0; mr < 4; ++mr) {
    const int ch = n0 + wr * 64 + mr * 16 + kg * 4;
    const float4 b4 = *(const float4*)(bias + ch);
#pragma unroll
    for (int nr = 0; nr < 4; ++nr) {
      const int qrow = m0 + wc * 64 + nr * 16 + l15;
      float4 v;
      v.x = acc[mr][nr][0] + b4.x;
      v.y = acc[mr][nr][1] + b4.y;
      v.z = acc[mr][nr][2] + b4.z;
      v.w = acc[mr][nr][3] + b4.w;
      *(float4*)(Cout + (size_t)qrow * N + ch) = v;
    }
  }
}

// ---------------- fused softmax + bilinear sampling (R7-proven) ----------------
__global__ __launch_bounds__(256)
void deform_sample_k(const ushort_t* __restrict__ value,   // bf16 (N,H,LIN,64)
                     const float* __restrict__ oa,         // (N*LQ, 512): off|logit
                     const float* __restrict__ refp,       // (N*LQ, 3, 2)
                     uint_t* __restrict__ otmp) {          // bf16 pairs (N*LQ, 192)
  __shared__ int4 sp[4][56];
  const int lane = threadIdx.x & 63, wv = threadIdx.x >> 6;
  const int wid = blockIdx.x * 4 + wv;
  const int s = wid >> 11;          // slice 0..23
  const int qq = wid & 2047;
  const int nb = s / HH, h = s - nb * HH;
  const int nq = nb * LQ + qq;

  float lg = -INFINITY;
  if (lane < 27) lg = oa[(size_t)nq * NOA + 324 + h * 27 + lane];
  float mx = lg;
#pragma unroll
  for (int m = 1; m < 64; m <<= 1) mx = fmaxf(mx, __shfl_xor(mx, m, 64));
  float e = (lane < 27) ? __expf(lg - mx) : 0.f;
  float ssum = e;
#pragma unroll
  for (int m = 1; m < 64; m <<= 1) ssum += __shfl_xor(ssum, m, 64);

  if (lane < 27) {
    const float aw = e / ssum;
    const int lvl = (lane >= 18) ? 2 : (lane >= 9 ? 1 : 0);
    const float Wf = (lvl == 0) ? 112.f : (lvl == 1 ? 56.f : 28.f);
    const int Wi = (lvl == 0) ? 112 : (lvl == 1 ? 56 : 28);
    const int base = (lvl == 0) ? 0 : (lvl == 1 ? 12544 : 15680);
    const float2 rp = *(const float2*)(refp + (size_t)nq * 6 + lvl * 2);
    const float2 of = *(const float2*)(oa + (size_t)nq * NOA + h * 54 + lane * 2);
    const float x = rp.x * Wf + of.x - 0.5f;
    const float y = rp.y * Wf + of.y - 0.5f;
    const float x0f = floorf(x), y0f = floorf(y);
    const float wx1 = x - x0f, wy1 = y - y0f;
    const float wx0 = 1.f - wx1, wy0 = 1.f - wy1;
    const int x0 = (int)x0f, y0 = (int)y0f;
    const int x1 = x0 + 1, y1 = y0 + 1;
    const bool bx0 = (x0 >= 0) & (x0 < Wi), bx1 = (x1 >= 0) & (x1 < Wi);
    const bool by0 = (y0 >= 0) & (y0 < Wi), by1 = (y1 >= 0) & (y1 < Wi);
    const int a00 = (bx0 & by0) ? ((base + y0 * Wi + x0) << 7) : 0;
    const int a01 = (bx1 & by0) ? ((base + y0 * Wi + x1) << 7) : 0;
    const int a10 = (bx0 & by1) ? ((base + y1 * Wi + x0) << 7) : 0;
    const int a11 = (bx1 & by1) ? ((base + y1 * Wi + x1) << 7) : 0;
    const float w00 = (bx0 & by0) ? aw * wx0 * wy0 : 0.f;
    const float w01 = (bx1 & by0) ? aw * wx1 * wy0 : 0.f;
    const float w10 = (bx0 & by1) ? aw * wx0 * wy1 : 0.f;
    const float w11 = (bx1 & by1) ? aw * wx1 * wy1 : 0.f;
    sp[wv][lane * 2 + 0] = make_int4(a00, __float_as_int(w00), a01, __float_as_int(w01));
    sp[wv][lane * 2 + 1] = make_int4(a10, __float_as_int(w10), a11, __float_as_int(w11));
  } else if (lane == 27) {
    sp[wv][54] = make_int4(0, 0, 0, 0);
    sp[wv][55] = make_int4(0, 0, 0, 0);
  }
  __syncthreads();

  const uint_t slice = (uint_t)__builtin_amdgcn_readfirstlane(s);
  const char* vbase = (const char*)value + (size_t)slice * (LIN * DH * 2);
  const int j4 = (lane & 31) * 4;
  const int half = lane >> 5;
  float a0 = 0.f, a1 = 0.f;
#pragma unroll 2
  for (int i = 0; i < 14; ++i) {
    const int pt = half * 14 + i;
    const int4 c01 = sp[wv][pt * 2];
    const int4 c23 = sp[wv][pt * 2 + 1];
    const uint_t u0 = *(const uint_t*)(vbase + (uint_t)(c01.x + j4));
    const uint_t u1 = *(const uint_t*)(vbase + (uint_t)(c01.z + j4));
    const uint_t u2 = *(const uint_t*)(vbase + (uint_t)(c23.x + j4));
    const uint_t u3 = *(const uint_t*)(vbase + (uint_t)(c23.z + j4));
    const float w0 = __int_as_float(c01.y), w1 = __int_as_float(c01.w);
    const float w2 = __int_as_float(c23.y), w3 = __int_as_float(c23.w);
    a0 += w0 * __uint_as_float(u0 << 16);
    a1 += w0 * __uint_as_float(u0 & 0xffff0000u);
    a0 += w1 * __uint_as_float(u1 << 16);
    a1 += w1 * __uint_as_float(u1 & 0xffff0000u);
    a0 += w2 * __uint_as_float(u2 << 16);
    a1 += w2 * __uint_as_float(u2 & 0xffff0000u);
    a0 += w3 * __uint_as_float(u3 << 16);
    a1 += w3 * __uint_as_float(u3 & 0xffff0000u);
  }
  a0 += __shfl_xor(a0, 32, 64);
  a1 += __shfl_xor(a1, 32, 64);
  if (lane < 32) {
    const uint_t packed = (uint_t)f2bf(a0) | ((uint_t)f2bf(a1) << 16);
    otmp[(size_t)nq * 192 + h * 32 + lane] = packed;
  }
}

// ---------------- launch ----------------
extern "C" void kernel_launch(void* const* d_in, const int* in_sizes, int n_in,
                              void* d_out, int out_size, void* d_ws, size_t ws_size,
                              hipStream_t stream) {
  const float* tgt   = (const float*)d_in[0];
  const float* src   = (const float*)d_in[1];
  const float* qpos  = (const float*)d_in[2];
  const float* refp  = (const float*)d_in[3];
  const float* W_off  = (const float*)d_in[7];
  const float* b_off  = (const float*)d_in[8];
  const float* W_attn = (const float*)d_in[9];
  const float* b_attn = (const float*)d_in[10];
  const float* W_val  = (const float*)d_in[11];
  const float* b_val  = (const float*)d_in[12];
  const float* W_out  = (const float*)d_in[13];
  const float* b_out  = (const float*)d_in[14];

  char* ws = (char*)d_ws;
  ushort_t* val_bf  = (ushort_t*)(ws);              // 50,577,408 B
  float*    oa      = (float*)   (ws + 50577408);   // 16,777,216
  ushort_t* q_bf    = (ushort_t*)(ws + 67354624);   //  4,194,304
  uint_t*   otmp    = (uint_t*)  (ws + 71548928);   //  6,291,456
  ushort_t* bt_val  = (ushort_t*)(ws + 77840384);   //    196,608
  ushort_t* bt_oa   = (ushort_t*)(ws + 78036992);   //    262,144
  ushort_t* bt_out  = (ushort_t*)(ws + 78299136);   //    196,608
  float*    bias_oa = (float*)   (ws + 78495744);   //      2,048

  // fused prep: q add+cvt, weight transposes, bias concat (src handled in-GEMM)
  prep_k<<<3330, 256, 0, stream>>>((const float4*)tgt, (const float4*)qpos,
                                   (ushort4*)q_bf, W_val, bt_val,
                                   W_off, W_attn, bt_oa, W_out, bt_out,
                                   b_off, b_attn, bias_oa);

  // value = src(fp32) @ W_val + b_val -> bf16 permuted (N,H,LIN,64)
  // 1029 row-chunks x 3 ch-tiles, cc fastest; barrier-free W-in-reg kernel
  mfma_gemm_vsrc_k<<<3087, 256, 0, stream>>>(src, bt_val, b_val, val_bf);
  // [off | logit] = q @ [W_off|W_attn] + bias (fp32, N=512): 64x4 tiles
  mfma_gemm_k<64, 4, 32><<<256, 256, 0, stream>>>(
      q_bf, bt_oa, bias_oa, oa, NOA, DM);

  // fused softmax + sampling -> otmp bf16
  deform_sample_k<<<12288, 256, 0, stream>>>(val_bf, oa, refp, otmp);

  // out = otmp @ W_out + b_out (fp32, final, K=384): 64x2 tiles
  mfma_gemm_k<64, 2, 16><<<128, 256, 0, stream>>>(
      (const ushort_t*)otmp, bt_out, b_out, (float*)d_out, DM, NVAL);
}

// Round 14
// 108.076 us; speedup vs baseline: 1.1635x; 1.1635x over previous
//
#include <hip/hip_runtime.h>
#include <math.h>

#define NB 4
#define LQ 2048
#define DM 256
#define HH 6
#define DH 64
#define LIN 16464
#define NOA 512             // fused off(324)+attn(162) padded
#define NVAL 384

typedef unsigned short ushort_t;
typedef unsigned int uint_t;
typedef __attribute__((ext_vector_type(8))) short s8v;   // 8 bf16 = 4 VGPR
typedef __attribute__((ext_vector_type(4))) float f4v;   // MFMA accumulator

__device__ __forceinline__ ushort_t f2bf(float f) {
  union { float f; unsigned u; } v; v.f = f;
  unsigned r = v.u + 0x7fffu + ((v.u >> 16) & 1u);  // RNE
  return (ushort_t)(r >> 16);
}

__device__ __forceinline__ uint_t cvtpk(float lo, float hi) {
  uint_t r;
  asm("v_cvt_pk_bf16_f32 %0, %1, %2" : "=v"(r) : "v"(lo), "v"(hi));
  return r;
}

typedef __attribute__((address_space(3))) char lds_char_t;
typedef const __attribute__((address_space(1))) char glb_char_t;
__device__ __forceinline__ void gload16(const void* g, void* l) {
  __builtin_amdgcn_global_load_lds((glb_char_t*)g, (lds_char_t*)l, 16, 0, 0);
}

// ---------------- fused prep: addq + weight transposes + bias ----------------
__global__ __launch_bounds__(256)
void prep_k(const float4* __restrict__ tgt, const float4* __restrict__ qpos,
            ushort4* __restrict__ q_bf,
            const float* __restrict__ W_val, ushort_t* __restrict__ bt_val,
            const float* __restrict__ W_off, const float* __restrict__ W_attn,
            ushort_t* __restrict__ bt_oa,
            const float* __restrict__ W_out, ushort_t* __restrict__ bt_out,
            const float* __restrict__ b_off, const float* __restrict__ b_attn,
            float* __restrict__ bias_oa) {
  const int blk = blockIdx.x, tid = threadIdx.x;
  if (blk < 2048) {
    const int i = blk * 256 + tid;
    float4 x = tgt[i], y = qpos[i];
    ushort4 r;
    r.x = f2bf(x.x + y.x); r.y = f2bf(x.y + y.y);
    r.z = f2bf(x.z + y.z); r.w = f2bf(x.w + y.w);
    q_bf[i] = r;
  } else {
    const int i = (blk - 2048) * 256 + tid;
    if (i < 98304) {              // bt_val[n][k] = W_val[k][n], 384x256
      const int n = i >> 8, k = i & 255;
      bt_val[i] = f2bf(W_val[(size_t)k * 384 + n]);
    } else if (i < 229376) {      // bt_oa: 512x256
      const int j = i - 98304;
      const int n = j >> 8, k = j & 255;
      float v = 0.f;
      if (n < 324) v = W_off[(size_t)k * 324 + n];
      else if (n < 486) v = W_attn[(size_t)k * 162 + (n - 324)];
      bt_oa[j] = f2bf(v);
    } else if (i < 327680) {      // bt_out: 256x384
      const int j = i - 229376;
      const int n = j / 384, k = j - n * 384;
      bt_out[j] = f2bf(W_out[(size_t)k * 256 + n]);
    } else {                      // bias_oa 512
      const int j = i - 327680;
      if (j < 512) bias_oa[j] = (j < 324) ? b_off[j] : (j < 486 ? b_attn[j - 324] : 0.f);
    }
  }
}

// ------------- value GEMM (R11-proven): fused fp32->bf16 act staging, depth-2 ----
template <int CPX>
__global__ __launch_bounds__(256)
void mfma_gemm_vsrc_k(const float* __restrict__ Src, const ushort_t* __restrict__ Wt,
                      const float* __restrict__ bias, ushort_t* __restrict__ Cout) {
  __shared__ char lds[3][16384];
  const int bid = blockIdx.x;
  const int r = (bid & 7) * CPX + (bid >> 3);
  if (r >= 1548) return;
  const int bx = r / 3, by = r - bx * 3;
  const int bq = bx / 129;                 // batch
  const int rb = (bx - bq * 129) * 128;    // row base within batch
  const int n0 = by * 128;                 // channels

  const int t = threadIdx.x;
  const int lane = t & 63, wid = t >> 6;
  const int wr = wid >> 1, wc = wid & 1;
  const int l15 = lane & 15, kg = lane >> 4;

  const int srow = lane >> 2;
  const int koct = (lane & 3) ^ ((lane >> 3) & 3);
  const int rsw = (l15 >> 1) & 3;
  const size_t WS0 = (size_t)(n0 + wid * 16 + srow) * DM + koct * 8;
  const size_t WS1 = WS0 + (size_t)64 * DM;

  const int ar = t >> 2, sA = t & 3;
  const int oA = sA ^ (((ar & 15) >> 1) & 3);
  const int rA0 = rb + ar, rA1 = rb + ar + 64;
  const float* pa = Src + ((size_t)bq * LIN + (rA0 < LIN ? rA0 : LIN - 1)) * DM + oA * 8;
  const float* pb = Src + ((size_t)bq * LIN + (rA1 < LIN ? rA1 : LIN - 1)) * DM + oA * 8;

  f4v acc[4][4];
#pragma unroll
  for (int i = 0; i < 4; ++i)
#pragma unroll
    for (int j = 0; j < 4; ++j) acc[i][j] = (f4v){0.f, 0.f, 0.f, 0.f};

  float4 lA[4], lB[4];

#define AL(dst_, g_)                                                     \
  { const int kb_ = (g_) << 5;                                           \
    dst_[0] = *(const float4*)(pa + kb_);                                \
    dst_[1] = *(const float4*)(pa + kb_ + 4);                            \
    dst_[2] = *(const float4*)(pb + kb_);                                \
    dst_[3] = *(const float4*)(pb + kb_ + 4); }

#define AW(src_, g_)                                                    \
  { char* d_ = &lds[(g_) % 3][8192] + t * 16;                           \
    uint4 c0, c1;                                                       \
    c0.x = cvtpk(src_[0].x, src_[0].y); c0.y = cvtpk(src_[0].z, src_[0].w); \
    c0.z = cvtpk(src_[1].x, src_[1].y); c0.w = cvtpk(src_[1].z, src_[1].w); \
    c1.x = cvtpk(src_[2].x, src_[2].y); c1.y = cvtpk(src_[2].z, src_[2].w); \
    c1.z = cvtpk(src_[3].x, src_[3].y); c1.w = cvtpk(src_[3].z, src_[3].w); \
    *(uint4*)(d_) = c0;                                                 \
    *(uint4*)(d_ + 4096) = c1; }

#define GW(g_)                                                          \
  { char* d_ = &lds[(g_) % 3][0]; const int ko_ = (g_) << 5;            \
    gload16(Wt + WS0 + ko_, d_ + wid * 1024);                           \
    gload16(Wt + WS1 + ko_, d_ + 4096 + wid * 1024); }

  AL(lA, 0);
  GW(0);
  asm volatile("s_waitcnt vmcnt(2)" ::: "memory");
  AW(lA, 0);
  AL(lA, 1);
  GW(1);
  asm volatile("s_waitcnt vmcnt(2)" ::: "memory");
  AW(lA, 1);
  AL(lA, 2);

#pragma unroll
  for (int gs = 0; gs < 8; ++gs) {
    if (gs <= 4) {
      if (gs & 1) { AL(lA, gs + 3); } else { AL(lB, gs + 3); }
    }
    if (gs == 7) asm volatile("s_waitcnt vmcnt(0)" ::: "memory");
    asm volatile("s_waitcnt lgkmcnt(0)" ::: "memory");
    __builtin_amdgcn_s_barrier();
    asm volatile("" ::: "memory");
    if (gs <= 5) GW(gs + 2);

    const char* d = &lds[gs % 3][0];
    s8v av[4], bv[4];
#pragma unroll
    for (int mr = 0; mr < 4; ++mr)
      av[mr] = *(const s8v*)(d + (wr * 64 + mr * 16 + l15) * 64 + ((kg ^ rsw) << 4));
#pragma unroll
    for (int nr = 0; nr < 4; ++nr)
      bv[nr] = *(const s8v*)(d + 8192 + (wc * 64 + nr * 16 + l15) * 64 + ((kg ^ rsw) << 4));
#pragma unroll
    for (int mr = 0; mr < 4; ++mr)
#pragma unroll
      for (int nr = 0; nr < 4; ++nr)
        acc[mr][nr] = __builtin_amdgcn_mfma_f32_16x16x32_bf16(av[mr], bv[nr],
                                                              acc[mr][nr], 0, 0, 0);

    if (gs <= 5) {
      if (gs <= 4) {
        asm volatile("s_waitcnt vmcnt(6)" ::: "memory");
      } else {
        asm volatile("s_waitcnt vmcnt(2)" ::: "memory");
      }
      if (gs & 1) { AW(lB, gs + 2); } else { AW(lA, gs + 2); }
    }
  }
#undef AL
#undef AW
#undef GW

#pragma unroll
  for (int mr = 0; mr < 4; ++mr) {
    const int ch = n0 + wr * 64 + mr * 16 + kg * 4;   // < 384
    const int h = ch >> 6, dd = ch & 63;
    const float4 b4 = *(const float4*)(bias + ch);
    ushort_t* obase = Cout + (size_t)(bq * HH + h) * LIN * DH + dd;
#pragma unroll
    for (int nr = 0; nr < 4; ++nr) {
      const int ii = rb + wc * 64 + nr * 16 + l15;
      if (ii < LIN) {
        ushort4 o;
        o.x = f2bf(acc[mr][nr][0] + b4.x);
        o.y = f2bf(acc[mr][nr][1] + b4.y);
        o.z = f2bf(acc[mr][nr][2] + b4.z);
        o.w = f2bf(acc[mr][nr][3] + b4.w);
        *(ushort4*)(obase + (size_t)ii * DH) = o;
      }
    }
  }
}

// ------------- bf16 MFMA GEMM (R7-proven), swapped operands, 128x128, 3-buf -------------
template <int NBX, int NBY, int CPX>
__global__ __launch_bounds__(256)
void mfma_gemm_k(const ushort_t* __restrict__ Act, const ushort_t* __restrict__ Wt,
                 const float* __restrict__ bias, float* __restrict__ Cout,
                 int N, int K) {
  __shared__ char lds[3][16384];
  const int bid = blockIdx.x;
  const int r = (bid & 7) * CPX + (bid >> 3);
  if (r >= NBX * NBY) return;
  const int bx = r / NBY, by = r - bx * NBY;
  const int m0 = bx * 128, n0 = by * 128;

  const int t = threadIdx.x;
  const int lane = t & 63, wid = t >> 6;
  const int wr = wid >> 1, wc = wid & 1;
  const int l15 = lane & 15, kg = lane >> 4;
  const int nk = K >> 5;

  const int srow = lane >> 2;
  const int koct = (lane & 3) ^ ((lane >> 3) & 3);
  const int rsw = (l15 >> 1) & 3;

  const size_t WA0 = (size_t)(n0 + wid * 16 + srow) * K + koct * 8;
  const size_t WA1 = WA0 + (size_t)64 * K;
  const size_t XB0 = (size_t)(m0 + wid * 16 + srow) * K + koct * 8;
  const size_t XB1 = XB0 + (size_t)64 * K;

  f4v acc[4][4];
#pragma unroll
  for (int i = 0; i < 4; ++i)
#pragma unroll
    for (int j = 0; j < 4; ++j) acc[i][j] = (f4v){0.f, 0.f, 0.f, 0.f};

#define STAGE(ks_)                                                       \
  { char* d_ = &lds[(ks_) % 3][0]; const int ko_ = (ks_) << 5;           \
    gload16(Wt + WA0 + ko_,  d_ + wid * 1024);                           \
    gload16(Wt + WA1 + ko_,  d_ + 4096 + wid * 1024);                    \
    gload16(Act + XB0 + ko_, d_ + 8192 + wid * 1024);                    \
    gload16(Act + XB1 + ko_, d_ + 12288 + wid * 1024); }

  STAGE(0);
  STAGE(1);

  for (int ks = 0; ks < nk; ++ks) {
    if (ks + 1 < nk) {
      asm volatile("s_waitcnt vmcnt(4)" ::: "memory");
    } else {
      asm volatile("s_waitcnt vmcnt(0)" ::: "memory");
    }
    __builtin_amdgcn_s_barrier();
    asm volatile("" ::: "memory");
    if (ks + 2 < nk) STAGE(ks + 2);

    const char* d = &lds[ks % 3][0];
    s8v av[4], bv[4];
#pragma unroll
    for (int mr = 0; mr < 4; ++mr)
      av[mr] = *(const s8v*)(d + (wr * 64 + mr * 16 + l15) * 64 + ((kg ^ rsw) << 4));
#pragma unroll
    for (int nr = 0; nr < 4; ++nr)
      bv[nr] = *(const s8v*)(d + 8192 + (wc * 64 + nr * 16 + l15) * 64 + ((kg ^ rsw) << 4));
#pragma unroll
    for (int mr = 0; mr < 4; ++mr)
#pragma unroll
      for (int nr = 0; nr < 4; ++nr)
        acc[mr][nr] = __builtin_amdgcn_mfma_f32_16x16x32_bf16(av[mr], bv[nr],
                                                              acc[mr][nr], 0, 0, 0);
  }
#undef STAGE

#pragma unroll
  for (int mr = 0; mr < 4; ++mr) {
    const int ch = n0 + wr * 64 + mr * 16 + kg * 4;
    const float4 b4 = *(const float4*)(bias + ch);
#pragma unroll
    for (int nr = 0; nr < 4; ++nr) {
      const int qrow = m0 + wc * 64 + nr * 16 + l15;
      float4 v;
      v.x = acc[mr][nr][0] + b4.x;
      v.y = acc[mr][nr][1] + b4.y;
      v.z = acc[mr][nr][2] + b4.z;
      v.w = acc[mr][nr][3] + b4.w;
      *(float4*)(Cout + (size_t)qrow * N + ch) = v;
    }
  }
}

// ---------------- fused softmax + bilinear sampling ----------------
// R7 structure + (a) FULL unroll of the 14-iter gather loop (deep MLP: up to 56
// loads in flight, VGPR headroom 24->~80), (b) s_setprio(1) around the gather.
__global__ __launch_bounds__(256)
void deform_sample_k(const ushort_t* __restrict__ value,   // bf16 (N,H,LIN,64)
                     const float* __restrict__ oa,         // (N*LQ, 512): off|logit
                     const float* __restrict__ refp,       // (N*LQ, 3, 2)
                     uint_t* __restrict__ otmp) {          // bf16 pairs (N*LQ, 192)
  __shared__ int4 sp[4][56];
  const int lane = threadIdx.x & 63, wv = threadIdx.x >> 6;
  const int wid = blockIdx.x * 4 + wv;
  const int s = wid >> 11;          // slice 0..23
  const int qq = wid & 2047;
  const int nb = s / HH, h = s - nb * HH;
  const int nq = nb * LQ + qq;

  float lg = -INFINITY;
  if (lane < 27) lg = oa[(size_t)nq * NOA + 324 + h * 27 + lane];
  float mx = lg;
#pragma unroll
  for (int m = 1; m < 64; m <<= 1) mx = fmaxf(mx, __shfl_xor(mx, m, 64));
  float e = (lane < 27) ? __expf(lg - mx) : 0.f;
  float ssum = e;
#pragma unroll
  for (int m = 1; m < 64; m <<= 1) ssum += __shfl_xor(ssum, m, 64);

  if (lane < 27) {
    const float aw = e / ssum;
    const int lvl = (lane >= 18) ? 2 : (lane >= 9 ? 1 : 0);
    const float Wf = (lvl == 0) ? 112.f : (lvl == 1 ? 56.f : 28.f);
    const int Wi = (lvl == 0) ? 112 : (lvl == 1 ? 56 : 28);
    const int base = (lvl == 0) ? 0 : (lvl == 1 ? 12544 : 15680);
    const float2 rp = *(const float2*)(refp + (size_t)nq * 6 + lvl * 2);
    const float2 of = *(const float2*)(oa + (size_t)nq * NOA + h * 54 + lane * 2);
    const float x = rp.x * Wf + of.x - 0.5f;
    const float y = rp.y * Wf + of.y - 0.5f;
    const float x0f = floorf(x), y0f = floorf(y);
    const float wx1 = x - x0f, wy1 = y - y0f;
    const float wx0 = 1.f - wx1, wy0 = 1.f - wy1;
    const int x0 = (int)x0f, y0 = (int)y0f;
    const int x1 = x0 + 1, y1 = y0 + 1;
    const bool bx0 = (x0 >= 0) & (x0 < Wi), bx1 = (x1 >= 0) & (x1 < Wi);
    const bool by0 = (y0 >= 0) & (y0 < Wi), by1 = (y1 >= 0) & (y1 < Wi);
    const int a00 = (bx0 & by0) ? ((base + y0 * Wi + x0) << 7) : 0;
    const int a01 = (bx1 & by0) ? ((base + y0 * Wi + x1) << 7) : 0;
    const int a10 = (bx0 & by1) ? ((base + y1 * Wi + x0) << 7) : 0;
    const int a11 = (bx1 & by1) ? ((base + y1 * Wi + x1) << 7) : 0;
    const float w00 = (bx0 & by0) ? aw * wx0 * wy0 : 0.f;
    const float w01 = (bx1 & by0) ? aw * wx1 * wy0 : 0.f;
    const float w10 = (bx0 & by1) ? aw * wx0 * wy1 : 0.f;
    const float w11 = (bx1 & by1) ? aw * wx1 * wy1 : 0.f;
    sp[wv][lane * 2 + 0] = make_int4(a00, __float_as_int(w00), a01, __float_as_int(w01));
    sp[wv][lane * 2 + 1] = make_int4(a10, __float_as_int(w10), a11, __float_as_int(w11));
  } else if (lane == 27) {
    sp[wv][54] = make_int4(0, 0, 0, 0);
    sp[wv][55] = make_int4(0, 0, 0, 0);
  }
  __syncthreads();

  const uint_t slice = (uint_t)__builtin_amdgcn_readfirstlane(s);
  const char* vbase = (const char*)value + (size_t)slice * (LIN * DH * 2);
  const int j4 = (lane & 31) * 4;
  const int half = lane >> 5;
  float a0 = 0.f, a1 = 0.f;
  __builtin_amdgcn_s_setprio(1);
#pragma unroll
  for (int i = 0; i < 14; ++i) {
    const int pt = half * 14 + i;
    const int4 c01 = sp[wv][pt * 2];
    const int4 c23 = sp[wv][pt * 2 + 1];
    const uint_t u0 = *(const uint_t*)(vbase + (uint_t)(c01.x + j4));
    const uint_t u1 = *(const uint_t*)(vbase + (uint_t)(c01.z + j4));
    const uint_t u2 = *(const uint_t*)(vbase + (uint_t)(c23.x + j4));
    const uint_t u3 = *(const uint_t*)(vbase + (uint_t)(c23.z + j4));
    const float w0 = __int_as_float(c01.y), w1 = __int_as_float(c01.w);
    const float w2 = __int_as_float(c23.y), w3 = __int_as_float(c23.w);
    a0 += w0 * __uint_as_float(u0 << 16);
    a1 += w0 * __uint_as_float(u0 & 0xffff0000u);
    a0 += w1 * __uint_as_float(u1 << 16);
    a1 += w1 * __uint_as_float(u1 & 0xffff0000u);
    a0 += w2 * __uint_as_float(u2 << 16);
    a1 += w2 * __uint_as_float(u2 & 0xffff0000u);
    a0 += w3 * __uint_as_float(u3 << 16);
    a1 += w3 * __uint_as_float(u3 & 0xffff0000u);
  }
  __builtin_amdgcn_s_setprio(0);
  a0 += __shfl_xor(a0, 32, 64);
  a1 += __shfl_xor(a1, 32, 64);
  if (lane < 32) {
    const uint_t packed = (uint_t)f2bf(a0) | ((uint_t)f2bf(a1) << 16);
    otmp[(size_t)nq * 192 + h * 32 + lane] = packed;
  }
}

// ---------------- launch ----------------
extern "C" void kernel_launch(void* const* d_in, const int* in_sizes, int n_in,
                              void* d_out, int out_size, void* d_ws, size_t ws_size,
                              hipStream_t stream) {
  const float* tgt   = (const float*)d_in[0];
  const float* src   = (const float*)d_in[1];
  const float* qpos  = (const float*)d_in[2];
  const float* refp  = (const float*)d_in[3];
  const float* W_off  = (const float*)d_in[7];
  const float* b_off  = (const float*)d_in[8];
  const float* W_attn = (const float*)d_in[9];
  const float* b_attn = (const float*)d_in[10];
  const float* W_val  = (const float*)d_in[11];
  const float* b_val  = (const float*)d_in[12];
  const float* W_out  = (const float*)d_in[13];
  const float* b_out  = (const float*)d_in[14];

  char* ws = (char*)d_ws;
  ushort_t* val_bf  = (ushort_t*)(ws);              // 50,577,408 B
  float*    oa      = (float*)   (ws + 50577408);   // 16,777,216
  ushort_t* q_bf    = (ushort_t*)(ws + 67354624);   //  4,194,304
  uint_t*   otmp    = (uint_t*)  (ws + 71548928);   //  6,291,456
  ushort_t* bt_val  = (ushort_t*)(ws + 77840384);   //    196,608
  ushort_t* bt_oa   = (ushort_t*)(ws + 78036992);   //    262,144
  ushort_t* bt_out  = (ushort_t*)(ws + 78299136);   //    196,608
  float*    bias_oa = (float*)   (ws + 78495744);   //      2,048

  // fused prep: q add+cvt, weight transposes, bias concat (src handled in-GEMM)
  prep_k<<<3330, 256, 0, stream>>>((const float4*)tgt, (const float4*)qpos,
                                   (ushort4*)q_bf, W_val, bt_val,
                                   W_off, W_attn, bt_oa, W_out, bt_out,
                                   b_off, b_attn, bias_oa);

  // value = src(fp32) @ W_val + b_val -> bf16 permuted (N,H,LIN,64)
  mfma_gemm_vsrc_k<194><<<1552, 256, 0, stream>>>(src, bt_val, b_val, val_bf);
  // [off | logit] = q @ [W_off|W_attn] + bias (fp32, N=512): 64x4 tiles
  mfma_gemm_k<64, 4, 32><<<256, 256, 0, stream>>>(
      q_bf, bt_oa, bias_oa, oa, NOA, DM);

  // fused softmax + sampling -> otmp bf16
  deform_sample_k<<<12288, 256, 0, stream>>>(val_bf, oa, refp, otmp);

  // out = otmp @ W_out + b_out (fp32, final, K=384): 64x2 tiles
  mfma_gemm_k<64, 2, 16><<<128, 256, 0, stream>>>(
      (const ushort_t*)otmp, bt_out, b_out, (float*)d_out, DM, NVAL);
}

// Round 16
// 107.670 us; speedup vs baseline: 1.1679x; 1.0038x over previous
//
#include <hip/hip_runtime.h>
#include <math.h>

#define NB 4
#define LQ 2048
#define DM 256
#define HH 6
#define DH 64
#define LIN 16464
#define NOA 512             // fused off(324)+attn(162) padded
#define NVAL 384

typedef unsigned short ushort_t;
typedef unsigned int uint_t;
typedef __attribute__((ext_vector_type(8))) short s8v;   // 8 bf16 = 4 VGPR
typedef __attribute__((ext_vector_type(4))) float f4v;   // MFMA accumulator

__device__ __forceinline__ ushort_t f2bf(float f) {
  union { float f; unsigned u; } v; v.f = f;
  unsigned r = v.u + 0x7fffu + ((v.u >> 16) & 1u);  // RNE
  return (ushort_t)(r >> 16);
}

__device__ __forceinline__ uint_t cvtpk(float lo, float hi) {
  uint_t r;
  asm("v_cvt_pk_bf16_f32 %0, %1, %2" : "=v"(r) : "v"(lo), "v"(hi));
  return r;
}

typedef __attribute__((address_space(3))) char lds_char_t;
typedef const __attribute__((address_space(1))) char glb_char_t;
__device__ __forceinline__ void gload16(const void* g, void* l) {
  __builtin_amdgcn_global_load_lds((glb_char_t*)g, (lds_char_t*)l, 16, 0, 0);
}

// ---------------- fused prep: addq + weight transposes + bias ----------------
__global__ __launch_bounds__(256)
void prep_k(const float4* __restrict__ tgt, const float4* __restrict__ qpos,
            ushort4* __restrict__ q_bf,
            const float* __restrict__ W_val, ushort_t* __restrict__ bt_val,
            const float* __restrict__ W_off, const float* __restrict__ W_attn,
            ushort_t* __restrict__ bt_oa,
            const float* __restrict__ W_out, ushort_t* __restrict__ bt_out,
            const float* __restrict__ b_off, const float* __restrict__ b_attn,
            float* __restrict__ bias_oa) {
  const int blk = blockIdx.x, tid = threadIdx.x;
  if (blk < 2048) {
    const int i = blk * 256 + tid;
    float4 x = tgt[i], y = qpos[i];
    ushort4 r;
    r.x = f2bf(x.x + y.x); r.y = f2bf(x.y + y.y);
    r.z = f2bf(x.z + y.z); r.w = f2bf(x.w + y.w);
    q_bf[i] = r;
  } else {
    const int i = (blk - 2048) * 256 + tid;
    if (i < 98304) {              // bt_val[n][k] = W_val[k][n], 384x256
      const int n = i >> 8, k = i & 255;
      bt_val[i] = f2bf(W_val[(size_t)k * 384 + n]);
    } else if (i < 229376) {      // bt_oa: 512x256
      const int j = i - 98304;
      const int n = j >> 8, k = j & 255;
      float v = 0.f;
      if (n < 324) v = W_off[(size_t)k * 324 + n];
      else if (n < 486) v = W_attn[(size_t)k * 162 + (n - 324)];
      bt_oa[j] = f2bf(v);
    } else if (i < 327680) {      // bt_out: 256x384
      const int j = i - 229376;
      const int n = j / 384, k = j - n * 384;
      bt_out[j] = f2bf(W_out[(size_t)k * 256 + n]);
    } else {                      // bias_oa 512
      const int j = i - 327680;
      if (j < 512) bias_oa[j] = (j < 324) ? b_off[j] : (j < 486 ? b_attn[j - 324] : 0.f);
    }
  }
}

// ------------- value GEMM (R11-proven): fused fp32->bf16 act staging, depth-2 ----
template <int CPX>
__global__ __launch_bounds__(256)
void mfma_gemm_vsrc_k(const float* __restrict__ Src, const ushort_t* __restrict__ Wt,
                      const float* __restrict__ bias, ushort_t* __restrict__ Cout) {
  __shared__ char lds[3][16384];
  const int bid = blockIdx.x;
  const int r = (bid & 7) * CPX + (bid >> 3);
  if (r >= 1548) return;
  const int bx = r / 3, by = r - bx * 3;
  const int bq = bx / 129;                 // batch
  const int rb = (bx - bq * 129) * 128;    // row base within batch
  const int n0 = by * 128;                 // channels

  const int t = threadIdx.x;
  const int lane = t & 63, wid = t >> 6;
  const int wr = wid >> 1, wc = wid & 1;
  const int l15 = lane & 15, kg = lane >> 4;

  const int srow = lane >> 2;
  const int koct = (lane & 3) ^ ((lane >> 3) & 3);
  const int rsw = (l15 >> 1) & 3;
  const size_t WS0 = (size_t)(n0 + wid * 16 + srow) * DM + koct * 8;
  const size_t WS1 = WS0 + (size_t)64 * DM;

  const int ar = t >> 2, sA = t & 3;
  const int oA = sA ^ (((ar & 15) >> 1) & 3);
  const int rA0 = rb + ar, rA1 = rb + ar + 64;
  const float* pa = Src + ((size_t)bq * LIN + (rA0 < LIN ? rA0 : LIN - 1)) * DM + oA * 8;
  const float* pb = Src + ((size_t)bq * LIN + (rA1 < LIN ? rA1 : LIN - 1)) * DM + oA * 8;

  f4v acc[4][4];
#pragma unroll
  for (int i = 0; i < 4; ++i)
#pragma unroll
    for (int j = 0; j < 4; ++j) acc[i][j] = (f4v){0.f, 0.f, 0.f, 0.f};

  float4 lA[4], lB[4];

#define AL(dst_, g_)                                                     \
  { const int kb_ = (g_) << 5;                                           \
    dst_[0] = *(const float4*)(pa + kb_);                                \
    dst_[1] = *(const float4*)(pa + kb_ + 4);                            \
    dst_[2] = *(const float4*)(pb + kb_);                                \
    dst_[3] = *(const float4*)(pb + kb_ + 4); }

#define AW(src_, g_)                                                    \
  { char* d_ = &lds[(g_) % 3][8192] + t * 16;                           \
    uint4 c0, c1;                                                       \
    c0.x = cvtpk(src_[0].x, src_[0].y); c0.y = cvtpk(src_[0].z, src_[0].w); \
    c0.z = cvtpk(src_[1].x, src_[1].y); c0.w = cvtpk(src_[1].z, src_[1].w); \
    c1.x = cvtpk(src_[2].x, src_[2].y); c1.y = cvtpk(src_[2].z, src_[2].w); \
    c1.z = cvtpk(src_[3].x, src_[3].y); c1.w = cvtpk(src_[3].z, src_[3].w); \
    *(uint4*)(d_) = c0;                                                 \
    *(uint4*)(d_ + 4096) = c1; }

#define GW(g_)                                                          \
  { char* d_ = &lds[(g_) % 3][0]; const int ko_ = (g_) << 5;            \
    gload16(Wt + WS0 + ko_, d_ + wid * 1024);                           \
    gload16(Wt + WS1 + ko_, d_ + 4096 + wid * 1024); }

  AL(lA, 0);
  GW(0);
  asm volatile("s_waitcnt vmcnt(2)" ::: "memory");
  AW(lA, 0);
  AL(lA, 1);
  GW(1);
  asm volatile("s_waitcnt vmcnt(2)" ::: "memory");
  AW(lA, 1);
  AL(lA, 2);

#pragma unroll
  for (int gs = 0; gs < 8; ++gs) {
    if (gs <= 4) {
      if (gs & 1) { AL(lA, gs + 3); } else { AL(lB, gs + 3); }
    }
    if (gs == 7) asm volatile("s_waitcnt vmcnt(0)" ::: "memory");
    asm volatile("s_waitcnt lgkmcnt(0)" ::: "memory");
    __builtin_amdgcn_s_barrier();
    asm volatile("" ::: "memory");
    if (gs <= 5) GW(gs + 2);

    const char* d = &lds[gs % 3][0];
    s8v av[4], bv[4];
#pragma unroll
    for (int mr = 0; mr < 4; ++mr)
      av[mr] = *(const s8v*)(d + (wr * 64 + mr * 16 + l15) * 64 + ((kg ^ rsw) << 4));
#pragma unroll
    for (int nr = 0; nr < 4; ++nr)
      bv[nr] = *(const s8v*)(d + 8192 + (wc * 64 + nr * 16 + l15) * 64 + ((kg ^ rsw) << 4));
#pragma unroll
    for (int mr = 0; mr < 4; ++mr)
#pragma unroll
      for (int nr = 0; nr < 4; ++nr)
        acc[mr][nr] = __builtin_amdgcn_mfma_f32_16x16x32_bf16(av[mr], bv[nr],
                                                              acc[mr][nr], 0, 0, 0);

    if (gs <= 5) {
      if (gs <= 4) {
        asm volatile("s_waitcnt vmcnt(6)" ::: "memory");
      } else {
        asm volatile("s_waitcnt vmcnt(2)" ::: "memory");
      }
      if (gs & 1) { AW(lB, gs + 2); } else { AW(lA, gs + 2); }
    }
  }
#undef AL
#undef AW
#undef GW

#pragma unroll
  for (int mr = 0; mr < 4; ++mr) {
    const int ch = n0 + wr * 64 + mr * 16 + kg * 4;   // < 384
    const int h = ch >> 6, dd = ch & 63;
    const float4 b4 = *(const float4*)(bias + ch);
    ushort_t* obase = Cout + (size_t)(bq * HH + h) * LIN * DH + dd;
#pragma unroll
    for (int nr = 0; nr < 4; ++nr) {
      const int ii = rb + wc * 64 + nr * 16 + l15;
      if (ii < LIN) {
        ushort4 o;
        o.x = f2bf(acc[mr][nr][0] + b4.x);
        o.y = f2bf(acc[mr][nr][1] + b4.y);
        o.z = f2bf(acc[mr][nr][2] + b4.z);
        o.w = f2bf(acc[mr][nr][3] + b4.w);
        *(ushort4*)(obase + (size_t)ii * DH) = o;
      }
    }
  }
}

// ------------- bf16 MFMA GEMM (R7-proven), swapped operands, 128x128, 3-buf -------------
template <int NBX, int NBY, int CPX>
__global__ __launch_bounds__(256)
void mfma_gemm_k(const ushort_t* __restrict__ Act, const ushort_t* __restrict__ Wt,
                 const float* __restrict__ bias, float* __restrict__ Cout,
                 int N, int K) {
  __shared__ char lds[3][16384];
  const int bid = blockIdx.x;
  const int r = (bid & 7) * CPX + (bid >> 3);
  if (r >= NBX * NBY) return;
  const int bx = r / NBY, by = r - bx * NBY;
  const int m0 = bx * 128, n0 = by * 128;

  const int t = threadIdx.x;
  const int lane = t & 63, wid = t >> 6;
  const int wr = wid >> 1, wc = wid & 1;
  const int l15 = lane & 15, kg = lane >> 4;
  const int nk = K >> 5;

  const int srow = lane >> 2;
  const int koct = (lane & 3) ^ ((lane >> 3) & 3);
  const int rsw = (l15 >> 1) & 3;

  const size_t WA0 = (size_t)(n0 + wid * 16 + srow) * K + koct * 8;
  const size_t WA1 = WA0 + (size_t)64 * K;
  const size_t XB0 = (size_t)(m0 + wid * 16 + srow) * K + koct * 8;
  const size_t XB1 = XB0 + (size_t)64 * K;

  f4v acc[4][4];
#pragma unroll
  for (int i = 0; i < 4; ++i)
#pragma unroll
    for (int j = 0; j < 4; ++j) acc[i][j] = (f4v){0.f, 0.f, 0.f, 0.f};

#define STAGE(ks_)                                                       \
  { char* d_ = &lds[(ks_) % 3][0]; const int ko_ = (ks_) << 5;           \
    gload16(Wt + WA0 + ko_,  d_ + wid * 1024);                           \
    gload16(Wt + WA1 + ko_,  d_ + 4096 + wid * 1024);                    \
    gload16(Act + XB0 + ko_, d_ + 8192 + wid * 1024);                    \
    gload16(Act + XB1 + ko_, d_ + 12288 + wid * 1024); }

  STAGE(0);
  STAGE(1);

  for (int ks = 0; ks < nk; ++ks) {
    if (ks + 1 < nk) {
      asm volatile("s_waitcnt vmcnt(4)" ::: "memory");
    } else {
      asm volatile("s_waitcnt vmcnt(0)" ::: "memory");
    }
    __builtin_amdgcn_s_barrier();
    asm volatile("" ::: "memory");
    if (ks + 2 < nk) STAGE(ks + 2);

    const char* d = &lds[ks % 3][0];
    s8v av[4], bv[4];
#pragma unroll
    for (int mr = 0; mr < 4; ++mr)
      av[mr] = *(const s8v*)(d + (wr * 64 + mr * 16 + l15) * 64 + ((kg ^ rsw) << 4));
#pragma unroll
    for (int nr = 0; nr < 4; ++nr)
      bv[nr] = *(const s8v*)(d + 8192 + (wc * 64 + nr * 16 + l15) * 64 + ((kg ^ rsw) << 4));
#pragma unroll
    for (int mr = 0; mr < 4; ++mr)
#pragma unroll
      for (int nr = 0; nr < 4; ++nr)
        acc[mr][nr] = __builtin_amdgcn_mfma_f32_16x16x32_bf16(av[mr], bv[nr],
                                                              acc[mr][nr], 0, 0, 0);
  }
#undef STAGE

#pragma unroll
  for (int mr = 0; mr < 4; ++mr) {
    const int ch = n0 + wr * 64 + mr * 16 + kg * 4;
    const float4 b4 = *(const float4*)(bias + ch);
#pragma unroll
    for (int nr = 0; nr < 4; ++nr) {
      const int qrow = m0 + wc * 64 + nr * 16 + l15;
      float4 v;
      v.x = acc[mr][nr][0] + b4.x;
      v.y = acc[mr][nr][1] + b4.y;
      v.z = acc[mr][nr][2] + b4.z;
      v.w = acc[mr][nr][3] + b4.w;
      *(float4*)(Cout + (size_t)qrow * N + ch) = v;
    }
  }
}

// ---------------- fused softmax + bilinear sampling (R14-proven) ----------------
__global__ __launch_bounds__(256)
void deform_sample_k(const ushort_t* __restrict__ value,   // bf16 (N,H,LIN,64)
                     const float* __restrict__ oa,         // (N*LQ, 512): off|logit
                     const float* __restrict__ refp,       // (N*LQ, 3, 2)
                     uint_t* __restrict__ otmp) {          // bf16 pairs (N*LQ, 192)
  __shared__ int4 sp[4][56];
  const int lane = threadIdx.x & 63, wv = threadIdx.x >> 6;
  const int wid = blockIdx.x * 4 + wv;
  const int s = wid >> 11;          // slice 0..23
  const int qq = wid & 2047;
  const int nb = s / HH, h = s - nb * HH;
  const int nq = nb * LQ + qq;

  float lg = -INFINITY;
  if (lane < 27) lg = oa[(size_t)nq * NOA + 324 + h * 27 + lane];
  float mx = lg;
#pragma unroll
  for (int m = 1; m < 64; m <<= 1) mx = fmaxf(mx, __shfl_xor(mx, m, 64));
  float e = (lane < 27) ? __expf(lg - mx) : 0.f;
  float ssum = e;
#pragma unroll
  for (int m = 1; m < 64; m <<= 1) ssum += __shfl_xor(ssum, m, 64);

  if (lane < 27) {
    const float aw = e / ssum;
    const int lvl = (lane >= 18) ? 2 : (lane >= 9 ? 1 : 0);
    const float Wf = (lvl == 0) ? 112.f : (lvl == 1 ? 56.f : 28.f);
    const int Wi = (lvl == 0) ? 112 : (lvl == 1 ? 56 : 28);
    const int base = (lvl == 0) ? 0 : (lvl == 1 ? 12544 : 15680);
    const float2 rp = *(const float2*)(refp + (size_t)nq * 6 + lvl * 2);
    const float2 of = *(const float2*)(oa + (size_t)nq * NOA + h * 54 + lane * 2);
    const float x = rp.x * Wf + of.x - 0.5f;
    const float y = rp.y * Wf + of.y - 0.5f;
    const float x0f = floorf(x), y0f = floorf(y);
    const float wx1 = x - x0f, wy1 = y - y0f;
    const float wx0 = 1.f - wx1, wy0 = 1.f - wy1;
    const int x0 = (int)x0f, y0 = (int)y0f;
    const int x1 = x0 + 1, y1 = y0 + 1;
    const bool bx0 = (x0 >= 0) & (x0 < Wi), bx1 = (x1 >= 0) & (x1 < Wi);
    const bool by0 = (y0 >= 0) & (y0 < Wi), by1 = (y1 >= 0) & (y1 < Wi);
    const int a00 = (bx0 & by0) ? ((base + y0 * Wi + x0) << 7) : 0;
    const int a01 = (bx1 & by0) ? ((base + y0 * Wi + x1) << 7) : 0;
    const int a10 = (bx0 & by1) ? ((base + y1 * Wi + x0) << 7) : 0;
    const int a11 = (bx1 & by1) ? ((base + y1 * Wi + x1) << 7) : 0;
    const float w00 = (bx0 & by0) ? aw * wx0 * wy0 : 0.f;
    const float w01 = (bx1 & by0) ? aw * wx1 * wy0 : 0.f;
    const float w10 = (bx0 & by1) ? aw * wx0 * wy1 : 0.f;
    const float w11 = (bx1 & by1) ? aw * wx1 * wy1 : 0.f;
    sp[wv][lane * 2 + 0] = make_int4(a00, __float_as_int(w00), a01, __float_as_int(w01));
    sp[wv][lane * 2 + 1] = make_int4(a10, __float_as_int(w10), a11, __float_as_int(w11));
  } else if (lane == 27) {
    sp[wv][54] = make_int4(0, 0, 0, 0);
    sp[wv][55] = make_int4(0, 0, 0, 0);
  }
  __syncthreads();

  const uint_t slice = (uint_t)__builtin_amdgcn_readfirstlane(s);
  const char* vbase = (const char*)value + (size_t)slice * (LIN * DH * 2);
  const int j4 = (lane & 31) * 4;
  const int half = lane >> 5;
  float a0 = 0.f, a1 = 0.f;
  __builtin_amdgcn_s_setprio(1);
#pragma unroll
  for (int i = 0; i < 14; ++i) {
    const int pt = half * 14 + i;
    const int4 c01 = sp[wv][pt * 2];
    const int4 c23 = sp[wv][pt * 2 + 1];
    const uint_t u0 = *(const uint_t*)(vbase + (uint_t)(c01.x + j4));
    const uint_t u1 = *(const uint_t*)(vbase + (uint_t)(c01.z + j4));
    const uint_t u2 = *(const uint_t*)(vbase + (uint_t)(c23.x + j4));
    const uint_t u3 = *(const uint_t*)(vbase + (uint_t)(c23.z + j4));
    const float w0 = __int_as_float(c01.y), w1 = __int_as_float(c01.w);
    const float w2 = __int_as_float(c23.y), w3 = __int_as_float(c23.w);
    a0 += w0 * __uint_as_float(u0 << 16);
    a1 += w0 * __uint_as_float(u0 & 0xffff0000u);
    a0 += w1 * __uint_as_float(u1 << 16);
    a1 += w1 * __uint_as_float(u1 & 0xffff0000u);
    a0 += w2 * __uint_as_float(u2 << 16);
    a1 += w2 * __uint_as_float(u2 & 0xffff0000u);
    a0 += w3 * __uint_as_float(u3 << 16);
    a1 += w3 * __uint_as_float(u3 & 0xffff0000u);
  }
  __builtin_amdgcn_s_setprio(0);
  a0 += __shfl_xor(a0, 32, 64);
  a1 += __shfl_xor(a1, 32, 64);
  if (lane < 32) {
    const uint_t packed = (uint_t)f2bf(a0) | ((uint_t)f2bf(a1) << 16);
    otmp[(size_t)nq * 192 + h * 32 + lane] = packed;
  }
}

// ---------------- launch ----------------
extern "C" void kernel_launch(void* const* d_in, const int* in_sizes, int n_in,
                              void* d_out, int out_size, void* d_ws, size_t ws_size,
                              hipStream_t stream) {
  const float* tgt   = (const float*)d_in[0];
  const float* src   = (const float*)d_in[1];
  const float* qpos  = (const float*)d_in[2];
  const float* refp  = (const float*)d_in[3];
  const float* W_off  = (const float*)d_in[7];
  const float* b_off  = (const float*)d_in[8];
  const float* W_attn = (const float*)d_in[9];
  const float* b_attn = (const float*)d_in[10];
  const float* W_val  = (const float*)d_in[11];
  const float* b_val  = (const float*)d_in[12];
  const float* W_out  = (const float*)d_in[13];
  const float* b_out  = (const float*)d_in[14];

  char* ws = (char*)d_ws;
  ushort_t* val_bf  = (ushort_t*)(ws);              // 50,577,408 B
  float*    oa      = (float*)   (ws + 50577408);   // 16,777,216
  ushort_t* q_bf    = (ushort_t*)(ws + 67354624);   //  4,194,304
  uint_t*   otmp    = (uint_t*)  (ws + 71548928);   //  6,291,456
  ushort_t* bt_val  = (ushort_t*)(ws + 77840384);   //    196,608
  ushort_t* bt_oa   = (ushort_t*)(ws + 78036992);   //    262,144
  ushort_t* bt_out  = (ushort_t*)(ws + 78299136);   //    196,608
  float*    bias_oa = (float*)   (ws + 78495744);   //      2,048

  // fused prep: q add+cvt, weight transposes, bias concat (src handled in-GEMM)
  prep_k<<<3330, 256, 0, stream>>>((const float4*)tgt, (const float4*)qpos,
                                   (ushort4*)q_bf, W_val, bt_val,
                                   W_off, W_attn, bt_oa, W_out, bt_out,
                                   b_off, b_attn, bias_oa);

  // value = src(fp32) @ W_val + b_val -> bf16 permuted (N,H,LIN,64)
  mfma_gemm_vsrc_k<194><<<1552, 256, 0, stream>>>(src, bt_val, b_val, val_bf);
  // [off | logit] = q @ [W_off|W_attn] + bias (fp32, N=512): 64x4 tiles
  mfma_gemm_k<64, 4, 32><<<256, 256, 0, stream>>>(
      q_bf, bt_oa, bias_oa, oa, NOA, DM);

  // fused softmax + sampling -> otmp bf16
  deform_sample_k<<<12288, 256, 0, stream>>>(val_bf, oa, refp, otmp);

  // out = otmp @ W_out + b_out (fp32, final, K=384): 64x2 tiles
  mfma_gemm_k<64, 2, 16><<<128, 256, 0, stream>>>(
      (const ushort_t*)otmp, bt_out, b_out, (float*)d_out, DM, NVAL);
}

// Round 17
// 100.133 us; speedup vs baseline: 1.2558x; 1.0753x over previous
//
#include <hip/hip_runtime.h>
#include <math.h>

#define NB 4
#define LQ 2048
#define DM 256
#define HH 6
#define DH 64
#define LIN 16464
#define NOA 512             // fused off(324)+attn(162) padded
#define NVAL 384

typedef unsigned short ushort_t;
typedef unsigned int uint_t;
typedef __attribute__((ext_vector_type(8))) short s8v;   // 8 bf16 = 4 VGPR
typedef __attribute__((ext_vector_type(4))) float f4v;   // MFMA accumulator

__device__ __forceinline__ ushort_t f2bf(float f) {
  union { float f; unsigned u; } v; v.f = f;
  unsigned r = v.u + 0x7fffu + ((v.u >> 16) & 1u);  // RNE
  return (ushort_t)(r >> 16);
}

__device__ __forceinline__ uint_t cvtpk(float lo, float hi) {
  uint_t r;
  asm("v_cvt_pk_bf16_f32 %0, %1, %2" : "=v"(r) : "v"(lo), "v"(hi));
  return r;
}

typedef __attribute__((address_space(3))) char lds_char_t;
typedef const __attribute__((address_space(1))) char glb_char_t;
__device__ __forceinline__ void gload16(const void* g, void* l) {
  __builtin_amdgcn_global_load_lds((glb_char_t*)g, (lds_char_t*)l, 16, 0, 0);
}

// ---------------- fused prep: addq + weight transposes + bias ----------------
__global__ __launch_bounds__(256)
void prep_k(const float4* __restrict__ tgt, const float4* __restrict__ qpos,
            ushort4* __restrict__ q_bf,
            const float* __restrict__ W_val, ushort_t* __restrict__ bt_val,
            const float* __restrict__ W_off, const float* __restrict__ W_attn,
            ushort_t* __restrict__ bt_oa,
            const float* __restrict__ W_out, ushort_t* __restrict__ bt_out,
            const float* __restrict__ b_off, const float* __restrict__ b_attn,
            float* __restrict__ bias_oa) {
  const int blk = blockIdx.x, tid = threadIdx.x;
  if (blk < 2048) {
    const int i = blk * 256 + tid;
    float4 x = tgt[i], y = qpos[i];
    ushort4 r;
    r.x = f2bf(x.x + y.x); r.y = f2bf(x.y + y.y);
    r.z = f2bf(x.z + y.z); r.w = f2bf(x.w + y.w);
    q_bf[i] = r;
  } else {
    const int i = (blk - 2048) * 256 + tid;
    if (i < 98304) {              // bt_val[n][k] = W_val[k][n], 384x256
      const int n = i >> 8, k = i & 255;
      bt_val[i] = f2bf(W_val[(size_t)k * 384 + n]);
    } else if (i < 229376) {      // bt_oa: 512x256
      const int j = i - 98304;
      const int n = j >> 8, k = j & 255;
      float v = 0.f;
      if (n < 324) v = W_off[(size_t)k * 324 + n];
      else if (n < 486) v = W_attn[(size_t)k * 162 + (n - 324)];
      bt_oa[j] = f2bf(v);
    } else if (i < 327680) {      // bt_out: 256x384
      const int j = i - 229376;
      const int n = j / 384, k = j - n * 384;
      bt_out[j] = f2bf(W_out[(size_t)k * 256 + n]);
    } else {                      // bias_oa 512
      const int j = i - 327680;
      if (j < 512) bias_oa[j] = (j < 324) ? b_off[j] : (j < 486 ? b_attn[j - 324] : 0.f);
    }
  }
}

// ------------- value GEMM (R11 K-loop) + COALESCED epilogue via wave-local LDS ----
// K-loop identical to R11/R14 (proven ledger). Epilogue: one __syncthreads (drain),
// each wave transposes its 64ch x 64row acc into a private 8KB scratch as [row][d]
// bf16 (XOR-swizzle (row&7)<<4, ~2-way banks), then 8x fully-coalesced 1KB stores
// (8 rows x 128B per inst) -- replaces 16x 8B/128B-stride partial-line stores.
template <int CPX>
__global__ __launch_bounds__(256)
void mfma_gemm_vsrc_k(const float* __restrict__ Src, const ushort_t* __restrict__ Wt,
                      const float* __restrict__ bias, ushort_t* __restrict__ Cout) {
  __shared__ char lds[3][16384];
  const int bid = blockIdx.x;
  const int r = (bid & 7) * CPX + (bid >> 3);
  if (r >= 1548) return;
  const int bx = r / 3, by = r - bx * 3;
  const int bq = bx / 129;                 // batch
  const int rb = (bx - bq * 129) * 128;    // row base within batch
  const int n0 = by * 128;                 // channels

  const int t = threadIdx.x;
  const int lane = t & 63, wid = t >> 6;
  const int wr = wid >> 1, wc = wid & 1;
  const int l15 = lane & 15, kg = lane >> 4;

  const int srow = lane >> 2;
  const int koct = (lane & 3) ^ ((lane >> 3) & 3);
  const int rsw = (l15 >> 1) & 3;
  const size_t WS0 = (size_t)(n0 + wid * 16 + srow) * DM + koct * 8;
  const size_t WS1 = WS0 + (size_t)64 * DM;

  const int ar = t >> 2, sA = t & 3;
  const int oA = sA ^ (((ar & 15) >> 1) & 3);
  const int rA0 = rb + ar, rA1 = rb + ar + 64;
  const float* pa = Src + ((size_t)bq * LIN + (rA0 < LIN ? rA0 : LIN - 1)) * DM + oA * 8;
  const float* pb = Src + ((size_t)bq * LIN + (rA1 < LIN ? rA1 : LIN - 1)) * DM + oA * 8;

  f4v acc[4][4];
#pragma unroll
  for (int i = 0; i < 4; ++i)
#pragma unroll
    for (int j = 0; j < 4; ++j) acc[i][j] = (f4v){0.f, 0.f, 0.f, 0.f};

  float4 lA[4], lB[4];

#define AL(dst_, g_)                                                     \
  { const int kb_ = (g_) << 5;                                           \
    dst_[0] = *(const float4*)(pa + kb_);                                \
    dst_[1] = *(const float4*)(pa + kb_ + 4);                            \
    dst_[2] = *(const float4*)(pb + kb_);                                \
    dst_[3] = *(const float4*)(pb + kb_ + 4); }

#define AW(src_, g_)                                                    \
  { char* d_ = &lds[(g_) % 3][8192] + t * 16;                           \
    uint4 c0, c1;                                                       \
    c0.x = cvtpk(src_[0].x, src_[0].y); c0.y = cvtpk(src_[0].z, src_[0].w); \
    c0.z = cvtpk(src_[1].x, src_[1].y); c0.w = cvtpk(src_[1].z, src_[1].w); \
    c1.x = cvtpk(src_[2].x, src_[2].y); c1.y = cvtpk(src_[2].z, src_[2].w); \
    c1.z = cvtpk(src_[3].x, src_[3].y); c1.w = cvtpk(src_[3].z, src_[3].w); \
    *(uint4*)(d_) = c0;                                                 \
    *(uint4*)(d_ + 4096) = c1; }

#define GW(g_)                                                          \
  { char* d_ = &lds[(g_) % 3][0]; const int ko_ = (g_) << 5;            \
    gload16(Wt + WS0 + ko_, d_ + wid * 1024);                           \
    gload16(Wt + WS1 + ko_, d_ + 4096 + wid * 1024); }

  AL(lA, 0);
  GW(0);
  asm volatile("s_waitcnt vmcnt(2)" ::: "memory");
  AW(lA, 0);
  AL(lA, 1);
  GW(1);
  asm volatile("s_waitcnt vmcnt(2)" ::: "memory");
  AW(lA, 1);
  AL(lA, 2);

#pragma unroll
  for (int gs = 0; gs < 8; ++gs) {
    if (gs <= 4) {
      if (gs & 1) { AL(lA, gs + 3); } else { AL(lB, gs + 3); }
    }
    if (gs == 7) asm volatile("s_waitcnt vmcnt(0)" ::: "memory");
    asm volatile("s_waitcnt lgkmcnt(0)" ::: "memory");
    __builtin_amdgcn_s_barrier();
    asm volatile("" ::: "memory");
    if (gs <= 5) GW(gs + 2);

    const char* d = &lds[gs % 3][0];
    s8v av[4], bv[4];
#pragma unroll
    for (int mr = 0; mr < 4; ++mr)
      av[mr] = *(const s8v*)(d + (wr * 64 + mr * 16 + l15) * 64 + ((kg ^ rsw) << 4));
#pragma unroll
    for (int nr = 0; nr < 4; ++nr)
      bv[nr] = *(const s8v*)(d + 8192 + (wc * 64 + nr * 16 + l15) * 64 + ((kg ^ rsw) << 4));
#pragma unroll
    for (int mr = 0; mr < 4; ++mr)
#pragma unroll
      for (int nr = 0; nr < 4; ++nr)
        acc[mr][nr] = __builtin_amdgcn_mfma_f32_16x16x32_bf16(av[mr], bv[nr],
                                                              acc[mr][nr], 0, 0, 0);

    if (gs <= 5) {
      if (gs <= 4) {
        asm volatile("s_waitcnt vmcnt(6)" ::: "memory");
      } else {
        asm volatile("s_waitcnt vmcnt(2)" ::: "memory");
      }
      if (gs & 1) { AW(lB, gs + 2); } else { AW(lA, gs + 2); }
    }
  }
#undef AL
#undef AW
#undef GW

  // ---- coalesced epilogue ----
  __syncthreads();   // all K-loop LDS reads drained; lds[] now free scratch
  char* scr = &lds[0][0] + wid * 8192;   // per-wave 8KB: [64 rows][128B d-range]
  // transpose acc -> scratch: row_local = nr*16+l15, d = mr*16+kg*4 (4 ch = 8B)
#pragma unroll
  for (int mr = 0; mr < 4; ++mr) {
    const int ch = n0 + wr * 64 + mr * 16 + kg * 4;
    const float4 b4 = *(const float4*)(bias + ch);
    const int dbyte = (mr * 16 + kg * 4) * 2;
#pragma unroll
    for (int nr = 0; nr < 4; ++nr) {
      const int rl = nr * 16 + l15;
      ushort4 o;
      o.x = f2bf(acc[mr][nr][0] + b4.x);
      o.y = f2bf(acc[mr][nr][1] + b4.y);
      o.z = f2bf(acc[mr][nr][2] + b4.z);
      o.w = f2bf(acc[mr][nr][3] + b4.w);
      *(ushort4*)(scr + ((rl * 128 + dbyte) ^ ((rl & 7) << 4))) = o;
    }
  }
  // read back full 128B rows, store 1KB-contiguous per inst (8 rows x 128B)
  const int h = (n0 + wr * 64) >> 6;       // wave's single h-slice (64-aligned)
  ushort_t* slice_base = Cout + (size_t)(bq * HH + h) * LIN * DH;
  const int row0 = rb + wc * 64;
  const int r8 = lane >> 3, seg = (lane & 7) * 16;
#pragma unroll
  for (int j = 0; j < 8; ++j) {
    const int rl = j * 8 + r8;
    uint4 v = *(const uint4*)(scr + ((rl * 128 + seg) ^ ((rl & 7) << 4)));
    const int ii = row0 + rl;
    if (ii < LIN)
      *(uint4*)((char*)(slice_base + (size_t)ii * DH) + seg) = v;
  }
}

// ------------- bf16 MFMA GEMM (R7-proven), swapped operands, 128x128, 3-buf -------------
template <int NBX, int NBY, int CPX>
__global__ __launch_bounds__(256)
void mfma_gemm_k(const ushort_t* __restrict__ Act, const ushort_t* __restrict__ Wt,
                 const float* __restrict__ bias, float* __restrict__ Cout,
                 int N, int K) {
  __shared__ char lds[3][16384];
  const int bid = blockIdx.x;
  const int r = (bid & 7) * CPX + (bid >> 3);
  if (r >= NBX * NBY) return;
  const int bx = r / NBY, by = r - bx * NBY;
  const int m0 = bx * 128, n0 = by * 128;

  const int t = threadIdx.x;
  const int lane = t & 63, wid = t >> 6;
  const int wr = wid >> 1, wc = wid & 1;
  const int l15 = lane & 15, kg = lane >> 4;
  const int nk = K >> 5;

  const int srow = lane >> 2;
  const int koct = (lane & 3) ^ ((lane >> 3) & 3);
  const int rsw = (l15 >> 1) & 3;

  const size_t WA0 = (size_t)(n0 + wid * 16 + srow) * K + koct * 8;
  const size_t WA1 = WA0 + (size_t)64 * K;
  const size_t XB0 = (size_t)(m0 + wid * 16 + srow) * K + koct * 8;
  const size_t XB1 = XB0 + (size_t)64 * K;

  f4v acc[4][4];
#pragma unroll
  for (int i = 0; i < 4; ++i)
#pragma unroll
    for (int j = 0; j < 4; ++j) acc[i][j] = (f4v){0.f, 0.f, 0.f, 0.f};

#define STAGE(ks_)                                                       \
  { char* d_ = &lds[(ks_) % 3][0]; const int ko_ = (ks_) << 5;           \
    gload16(Wt + WA0 + ko_,  d_ + wid * 1024);                           \
    gload16(Wt + WA1 + ko_,  d_ + 4096 + wid * 1024);                    \
    gload16(Act + XB0 + ko_, d_ + 8192 + wid * 1024);                    \
    gload16(Act + XB1 + ko_, d_ + 12288 + wid * 1024); }

  STAGE(0);
  STAGE(1);

  for (int ks = 0; ks < nk; ++ks) {
    if (ks + 1 < nk) {
      asm volatile("s_waitcnt vmcnt(4)" ::: "memory");
    } else {
      asm volatile("s_waitcnt vmcnt(0)" ::: "memory");
    }
    __builtin_amdgcn_s_barrier();
    asm volatile("" ::: "memory");
    if (ks + 2 < nk) STAGE(ks + 2);

    const char* d = &lds[ks % 3][0];
    s8v av[4], bv[4];
#pragma unroll
    for (int mr = 0; mr < 4; ++mr)
      av[mr] = *(const s8v*)(d + (wr * 64 + mr * 16 + l15) * 64 + ((kg ^ rsw) << 4));
#pragma unroll
    for (int nr = 0; nr < 4; ++nr)
      bv[nr] = *(const s8v*)(d + 8192 + (wc * 64 + nr * 16 + l15) * 64 + ((kg ^ rsw) << 4));
#pragma unroll
    for (int mr = 0; mr < 4; ++mr)
#pragma unroll
      for (int nr = 0; nr < 4; ++nr)
        acc[mr][nr] = __builtin_amdgcn_mfma_f32_16x16x32_bf16(av[mr], bv[nr],
                                                              acc[mr][nr], 0, 0, 0);
  }
#undef STAGE

#pragma unroll
  for (int mr = 0; mr < 4; ++mr) {
    const int ch = n0 + wr * 64 + mr * 16 + kg * 4;
    const float4 b4 = *(const float4*)(bias + ch);
#pragma unroll
    for (int nr = 0; nr < 4; ++nr) {
      const int qrow = m0 + wc * 64 + nr * 16 + l15;
      float4 v;
      v.x = acc[mr][nr][0] + b4.x;
      v.y = acc[mr][nr][1] + b4.y;
      v.z = acc[mr][nr][2] + b4.z;
      v.w = acc[mr][nr][3] + b4.w;
      *(float4*)(Cout + (size_t)qrow * N + ch) = v;
    }
  }
}

// ---------------- fused softmax + bilinear sampling (R14-proven) ----------------
__global__ __launch_bounds__(256)
void deform_sample_k(const ushort_t* __restrict__ value,   // bf16 (N,H,LIN,64)
                     const float* __restrict__ oa,         // (N*LQ, 512): off|logit
                     const float* __restrict__ refp,       // (N*LQ, 3, 2)
                     uint_t* __restrict__ otmp) {          // bf16 pairs (N*LQ, 192)
  __shared__ int4 sp[4][56];
  const int lane = threadIdx.x & 63, wv = threadIdx.x >> 6;
  const int wid = blockIdx.x * 4 + wv;
  const int s = wid >> 11;          // slice 0..23
  const int qq = wid & 2047;
  const int nb = s / HH, h = s - nb * HH;
  const int nq = nb * LQ + qq;

  float lg = -INFINITY;
  if (lane < 27) lg = oa[(size_t)nq * NOA + 324 + h * 27 + lane];
  float mx = lg;
#pragma unroll
  for (int m = 1; m < 64; m <<= 1) mx = fmaxf(mx, __shfl_xor(mx, m, 64));
  float e = (lane < 27) ? __expf(lg - mx) : 0.f;
  float ssum = e;
#pragma unroll
  for (int m = 1; m < 64; m <<= 1) ssum += __shfl_xor(ssum, m, 64);

  if (lane < 27) {
    const float aw = e / ssum;
    const int lvl = (lane >= 18) ? 2 : (lane >= 9 ? 1 : 0);
    const float Wf = (lvl == 0) ? 112.f : (lvl == 1 ? 56.f : 28.f);
    const int Wi = (lvl == 0) ? 112 : (lvl == 1 ? 56 : 28);
    const int base = (lvl == 0) ? 0 : (lvl == 1 ? 12544 : 15680);
    const float2 rp = *(const float2*)(refp + (size_t)nq * 6 + lvl * 2);
    const float2 of = *(const float2*)(oa + (size_t)nq * NOA + h * 54 + lane * 2);
    const float x = rp.x * Wf + of.x - 0.5f;
    const float y = rp.y * Wf + of.y - 0.5f;
    const float x0f = floorf(x), y0f = floorf(y);
    const float wx1 = x - x0f, wy1 = y - y0f;
    const float wx0 = 1.f - wx1, wy0 = 1.f - wy1;
    const int x0 = (int)x0f, y0 = (int)y0f;
    const int x1 = x0 + 1, y1 = y0 + 1;
    const bool bx0 = (x0 >= 0) & (x0 < Wi), bx1 = (x1 >= 0) & (x1 < Wi);
    const bool by0 = (y0 >= 0) & (y0 < Wi), by1 = (y1 >= 0) & (y1 < Wi);
    const int a00 = (bx0 & by0) ? ((base + y0 * Wi + x0) << 7) : 0;
    const int a01 = (bx1 & by0) ? ((base + y0 * Wi + x1) << 7) : 0;
    const int a10 = (bx0 & by1) ? ((base + y1 * Wi + x0) << 7) : 0;
    const int a11 = (bx1 & by1) ? ((base + y1 * Wi + x1) << 7) : 0;
    const float w00 = (bx0 & by0) ? aw * wx0 * wy0 : 0.f;
    const float w01 = (bx1 & by0) ? aw * wx1 * wy0 : 0.f;
    const float w10 = (bx0 & by1) ? aw * wx0 * wy1 : 0.f;
    const float w11 = (bx1 & by1) ? aw * wx1 * wy1 : 0.f;
    sp[wv][lane * 2 + 0] = make_int4(a00, __float_as_int(w00), a01, __float_as_int(w01));
    sp[wv][lane * 2 + 1] = make_int4(a10, __float_as_int(w10), a11, __float_as_int(w11));
  } else if (lane == 27) {
    sp[wv][54] = make_int4(0, 0, 0, 0);
    sp[wv][55] = make_int4(0, 0, 0, 0);
  }
  __syncthreads();

  const uint_t slice = (uint_t)__builtin_amdgcn_readfirstlane(s);
  const char* vbase = (const char*)value + (size_t)slice * (LIN * DH * 2);
  const int j4 = (lane & 31) * 4;
  const int half = lane >> 5;
  float a0 = 0.f, a1 = 0.f;
  __builtin_amdgcn_s_setprio(1);
#pragma unroll
  for (int i = 0; i < 14; ++i) {
    const int pt = half * 14 + i;
    const int4 c01 = sp[wv][pt * 2];
    const int4 c23 = sp[wv][pt * 2 + 1];
    const uint_t u0 = *(const uint_t*)(vbase + (uint_t)(c01.x + j4));
    const uint_t u1 = *(const uint_t*)(vbase + (uint_t)(c01.z + j4));
    const uint_t u2 = *(const uint_t*)(vbase + (uint_t)(c23.x + j4));
    const uint_t u3 = *(const uint_t*)(vbase + (uint_t)(c23.z + j4));
    const float w0 = __int_as_float(c01.y), w1 = __int_as_float(c01.w);
    const float w2 = __int_as_float(c23.y), w3 = __int_as_float(c23.w);
    a0 += w0 * __uint_as_float(u0 << 16);
    a1 += w0 * __uint_as_float(u0 & 0xffff0000u);
    a0 += w1 * __uint_as_float(u1 << 16);
    a1 += w1 * __uint_as_float(u1 & 0xffff0000u);
    a0 += w2 * __uint_as_float(u2 << 16);
    a1 += w2 * __uint_as_float(u2 & 0xffff0000u);
    a0 += w3 * __uint_as_float(u3 << 16);
    a1 += w3 * __uint_as_float(u3 & 0xffff0000u);
  }
  __builtin_amdgcn_s_setprio(0);
  a0 += __shfl_xor(a0, 32, 64);
  a1 += __shfl_xor(a1, 32, 64);
  if (lane < 32) {
    const uint_t packed = (uint_t)f2bf(a0) | ((uint_t)f2bf(a1) << 16);
    otmp[(size_t)nq * 192 + h * 32 + lane] = packed;
  }
}

// ---------------- launch ----------------
extern "C" void kernel_launch(void* const* d_in, const int* in_sizes, int n_in,
                              void* d_out, int out_size, void* d_ws, size_t ws_size,
                              hipStream_t stream) {
  const float* tgt   = (const float*)d_in[0];
  const float* src   = (const float*)d_in[1];
  const float* qpos  = (const float*)d_in[2];
  const float* refp  = (const float*)d_in[3];
  const float* W_off  = (const float*)d_in[7];
  const float* b_off  = (const float*)d_in[8];
  const float* W_attn = (const float*)d_in[9];
  const float* b_attn = (const float*)d_in[10];
  const float* W_val  = (const float*)d_in[11];
  const float* b_val  = (const float*)d_in[12];
  const float* W_out  = (const float*)d_in[13];
  const float* b_out  = (const float*)d_in[14];

  char* ws = (char*)d_ws;
  ushort_t* val_bf  = (ushort_t*)(ws);              // 50,577,408 B
  float*    oa      = (float*)   (ws + 50577408);   // 16,777,216
  ushort_t* q_bf    = (ushort_t*)(ws + 67354624);   //  4,194,304
  uint_t*   otmp    = (uint_t*)  (ws + 71548928);   //  6,291,456
  ushort_t* bt_val  = (ushort_t*)(ws + 77840384);   //    196,608
  ushort_t* bt_oa   = (ushort_t*)(ws + 78036992);   //    262,144
  ushort_t* bt_out  = (ushort_t*)(ws + 78299136);   //    196,608
  float*    bias_oa = (float*)   (ws + 78495744);   //      2,048

  // fused prep: q add+cvt, weight transposes, bias concat (src handled in-GEMM)
  prep_k<<<3330, 256, 0, stream>>>((const float4*)tgt, (const float4*)qpos,
                                   (ushort4*)q_bf, W_val, bt_val,
                                   W_off, W_attn, bt_oa, W_out, bt_out,
                                   b_off, b_attn, bias_oa);

  // value = src(fp32) @ W_val + b_val -> bf16 permuted (N,H,LIN,64)
  mfma_gemm_vsrc_k<194><<<1552, 256, 0, stream>>>(src, bt_val, b_val, val_bf);
  // [off | logit] = q @ [W_off|W_attn] + bias (fp32, N=512): 64x4 tiles
  mfma_gemm_k<64, 4, 32><<<256, 256, 0, stream>>>(
      q_bf, bt_oa, bias_oa, oa, NOA, DM);

  // fused softmax + sampling -> otmp bf16
  deform_sample_k<<<12288, 256, 0, stream>>>(val_bf, oa, refp, otmp);

  // out = otmp @ W_out + b_out (fp32, final, K=384): 64x2 tiles
  mfma_gemm_k<64, 2, 16><<<128, 256, 0, stream>>>(
      (const ushort_t*)otmp, bt_out, b_out, (float*)d_out, DM, NVAL);
}

// Round 18
// 98.705 us; speedup vs baseline: 1.2740x; 1.0145x over previous
//
#include <hip/hip_runtime.h>
#include <math.h>

#define NB 4
#define LQ 2048
#define DM 256
#define HH 6
#define DH 64
#define LIN 16464
#define NOA 512             // fused off(324)+attn(162) padded
#define NVAL 384

typedef unsigned short ushort_t;
typedef unsigned int uint_t;
typedef __attribute__((ext_vector_type(8))) short s8v;   // 8 bf16 = 4 VGPR
typedef __attribute__((ext_vector_type(4))) float f4v;   // MFMA accumulator

__device__ __forceinline__ ushort_t f2bf(float f) {
  union { float f; unsigned u; } v; v.f = f;
  unsigned r = v.u + 0x7fffu + ((v.u >> 16) & 1u);  // RNE
  return (ushort_t)(r >> 16);
}

__device__ __forceinline__ uint_t cvtpk(float lo, float hi) {
  uint_t r;
  asm("v_cvt_pk_bf16_f32 %0, %1, %2" : "=v"(r) : "v"(lo), "v"(hi));
  return r;
}

typedef __attribute__((address_space(3))) char lds_char_t;
typedef const __attribute__((address_space(1))) char glb_char_t;
__device__ __forceinline__ void gload16(const void* g, void* l) {
  __builtin_amdgcn_global_load_lds((glb_char_t*)g, (lds_char_t*)l, 16, 0, 0);
}

// ---------------- fused prep: addq + weight transposes + bias ----------------
__global__ __launch_bounds__(256)
void prep_k(const float4* __restrict__ tgt, const float4* __restrict__ qpos,
            ushort4* __restrict__ q_bf,
            const float* __restrict__ W_val, ushort_t* __restrict__ bt_val,
            const float* __restrict__ W_off, const float* __restrict__ W_attn,
            ushort_t* __restrict__ bt_oa,
            const float* __restrict__ W_out, ushort_t* __restrict__ bt_out,
            const float* __restrict__ b_off, const float* __restrict__ b_attn,
            float* __restrict__ bias_oa) {
  const int blk = blockIdx.x, tid = threadIdx.x;
  if (blk < 2048) {
    const int i = blk * 256 + tid;
    float4 x = tgt[i], y = qpos[i];
    ushort4 r;
    r.x = f2bf(x.x + y.x); r.y = f2bf(x.y + y.y);
    r.z = f2bf(x.z + y.z); r.w = f2bf(x.w + y.w);
    q_bf[i] = r;
  } else {
    const int i = (blk - 2048) * 256 + tid;
    if (i < 98304) {              // bt_val[n][k] = W_val[k][n], 384x256
      const int n = i >> 8, k = i & 255;
      bt_val[i] = f2bf(W_val[(size_t)k * 384 + n]);
    } else if (i < 229376) {      // bt_oa: 512x256
      const int j = i - 98304;
      const int n = j >> 8, k = j & 255;
      float v = 0.f;
      if (n < 324) v = W_off[(size_t)k * 324 + n];
      else if (n < 486) v = W_attn[(size_t)k * 162 + (n - 324)];
      bt_oa[j] = f2bf(v);
    } else if (i < 327680) {      // bt_out: 256x384
      const int j = i - 229376;
      const int n = j / 384, k = j - n * 384;
      bt_out[j] = f2bf(W_out[(size_t)k * 256 + n]);
    } else {                      // bias_oa 512
      const int j = i - 327680;
      if (j < 512) bias_oa[j] = (j < 324) ? b_off[j] : (j < 486 ? b_attn[j - 324] : 0.f);
    }
  }
}

// ------------- value GEMM (R17-proven): R11 K-loop + coalesced LDS-transpose epilogue ----
template <int CPX>
__global__ __launch_bounds__(256)
void mfma_gemm_vsrc_k(const float* __restrict__ Src, const ushort_t* __restrict__ Wt,
                      const float* __restrict__ bias, ushort_t* __restrict__ Cout) {
  __shared__ char lds[3][16384];
  const int bid = blockIdx.x;
  const int r = (bid & 7) * CPX + (bid >> 3);
  if (r >= 1548) return;
  const int bx = r / 3, by = r - bx * 3;
  const int bq = bx / 129;                 // batch
  const int rb = (bx - bq * 129) * 128;    // row base within batch
  const int n0 = by * 128;                 // channels

  const int t = threadIdx.x;
  const int lane = t & 63, wid = t >> 6;
  const int wr = wid >> 1, wc = wid & 1;
  const int l15 = lane & 15, kg = lane >> 4;

  const int srow = lane >> 2;
  const int koct = (lane & 3) ^ ((lane >> 3) & 3);
  const int rsw = (l15 >> 1) & 3;
  const size_t WS0 = (size_t)(n0 + wid * 16 + srow) * DM + koct * 8;
  const size_t WS1 = WS0 + (size_t)64 * DM;

  const int ar = t >> 2, sA = t & 3;
  const int oA = sA ^ (((ar & 15) >> 1) & 3);
  const int rA0 = rb + ar, rA1 = rb + ar + 64;
  const float* pa = Src + ((size_t)bq * LIN + (rA0 < LIN ? rA0 : LIN - 1)) * DM + oA * 8;
  const float* pb = Src + ((size_t)bq * LIN + (rA1 < LIN ? rA1 : LIN - 1)) * DM + oA * 8;

  f4v acc[4][4];
#pragma unroll
  for (int i = 0; i < 4; ++i)
#pragma unroll
    for (int j = 0; j < 4; ++j) acc[i][j] = (f4v){0.f, 0.f, 0.f, 0.f};

  float4 lA[4], lB[4];

#define AL(dst_, g_)                                                     \
  { const int kb_ = (g_) << 5;                                           \
    dst_[0] = *(const float4*)(pa + kb_);                                \
    dst_[1] = *(const float4*)(pa + kb_ + 4);                            \
    dst_[2] = *(const float4*)(pb + kb_);                                \
    dst_[3] = *(const float4*)(pb + kb_ + 4); }

#define AW(src_, g_)                                                    \
  { char* d_ = &lds[(g_) % 3][8192] + t * 16;                           \
    uint4 c0, c1;                                                       \
    c0.x = cvtpk(src_[0].x, src_[0].y); c0.y = cvtpk(src_[0].z, src_[0].w); \
    c0.z = cvtpk(src_[1].x, src_[1].y); c0.w = cvtpk(src_[1].z, src_[1].w); \
    c1.x = cvtpk(src_[2].x, src_[2].y); c1.y = cvtpk(src_[2].z, src_[2].w); \
    c1.z = cvtpk(src_[3].x, src_[3].y); c1.w = cvtpk(src_[3].z, src_[3].w); \
    *(uint4*)(d_) = c0;                                                 \
    *(uint4*)(d_ + 4096) = c1; }

#define GW(g_)                                                          \
  { char* d_ = &lds[(g_) % 3][0]; const int ko_ = (g_) << 5;            \
    gload16(Wt + WS0 + ko_, d_ + wid * 1024);                           \
    gload16(Wt + WS1 + ko_, d_ + 4096 + wid * 1024); }

  AL(lA, 0);
  GW(0);
  asm volatile("s_waitcnt vmcnt(2)" ::: "memory");
  AW(lA, 0);
  AL(lA, 1);
  GW(1);
  asm volatile("s_waitcnt vmcnt(2)" ::: "memory");
  AW(lA, 1);
  AL(lA, 2);

#pragma unroll
  for (int gs = 0; gs < 8; ++gs) {
    if (gs <= 4) {
      if (gs & 1) { AL(lA, gs + 3); } else { AL(lB, gs + 3); }
    }
    if (gs == 7) asm volatile("s_waitcnt vmcnt(0)" ::: "memory");
    asm volatile("s_waitcnt lgkmcnt(0)" ::: "memory");
    __builtin_amdgcn_s_barrier();
    asm volatile("" ::: "memory");
    if (gs <= 5) GW(gs + 2);

    const char* d = &lds[gs % 3][0];
    s8v av[4], bv[4];
#pragma unroll
    for (int mr = 0; mr < 4; ++mr)
      av[mr] = *(const s8v*)(d + (wr * 64 + mr * 16 + l15) * 64 + ((kg ^ rsw) << 4));
#pragma unroll
    for (int nr = 0; nr < 4; ++nr)
      bv[nr] = *(const s8v*)(d + 8192 + (wc * 64 + nr * 16 + l15) * 64 + ((kg ^ rsw) << 4));
#pragma unroll
    for (int mr = 0; mr < 4; ++mr)
#pragma unroll
      for (int nr = 0; nr < 4; ++nr)
        acc[mr][nr] = __builtin_amdgcn_mfma_f32_16x16x32_bf16(av[mr], bv[nr],
                                                              acc[mr][nr], 0, 0, 0);

    if (gs <= 5) {
      if (gs <= 4) {
        asm volatile("s_waitcnt vmcnt(6)" ::: "memory");
      } else {
        asm volatile("s_waitcnt vmcnt(2)" ::: "memory");
      }
      if (gs & 1) { AW(lB, gs + 2); } else { AW(lA, gs + 2); }
    }
  }
#undef AL
#undef AW
#undef GW

  // ---- coalesced epilogue (R17-proven) ----
  __syncthreads();   // all K-loop LDS reads drained; lds[] now free scratch
  char* scr = &lds[0][0] + wid * 8192;   // per-wave 8KB: [64 rows][128B d-range]
#pragma unroll
  for (int mr = 0; mr < 4; ++mr) {
    const int ch = n0 + wr * 64 + mr * 16 + kg * 4;
    const float4 b4 = *(const float4*)(bias + ch);
    const int dbyte = (mr * 16 + kg * 4) * 2;
#pragma unroll
    for (int nr = 0; nr < 4; ++nr) {
      const int rl = nr * 16 + l15;
      ushort4 o;
      o.x = f2bf(acc[mr][nr][0] + b4.x);
      o.y = f2bf(acc[mr][nr][1] + b4.y);
      o.z = f2bf(acc[mr][nr][2] + b4.z);
      o.w = f2bf(acc[mr][nr][3] + b4.w);
      *(ushort4*)(scr + ((rl * 128 + dbyte) ^ ((rl & 7) << 4))) = o;
    }
  }
  const int h = (n0 + wr * 64) >> 6;       // wave's single h-slice (64-aligned)
  ushort_t* slice_base = Cout + (size_t)(bq * HH + h) * LIN * DH;
  const int row0 = rb + wc * 64;
  const int r8 = lane >> 3, seg = (lane & 7) * 16;
#pragma unroll
  for (int j = 0; j < 8; ++j) {
    const int rl = j * 8 + r8;
    uint4 v = *(const uint4*)(scr + ((rl * 128 + seg) ^ ((rl & 7) << 4)));
    const int ii = row0 + rl;
    if (ii < LIN)
      *(uint4*)((char*)(slice_base + (size_t)ii * DH) + seg) = v;
  }
}

// ------------- bf16 MFMA GEMM (R7 K-loop) + coalesced 2-pass fp32 epilogue -------------
// Epilogue: wave-local LDS transpose (2 passes of 32 ch, [64 rows][128B] scratch,
// XOR swizzle (rl&7)<<4), then full-line stores: 8 rows x 128B per inst.
template <int NBX, int NBY, int CPX>
__global__ __launch_bounds__(256)
void mfma_gemm_k(const ushort_t* __restrict__ Act, const ushort_t* __restrict__ Wt,
                 const float* __restrict__ bias, float* __restrict__ Cout,
                 int N, int K) {
  __shared__ char lds[3][16384];
  const int bid = blockIdx.x;
  const int r = (bid & 7) * CPX + (bid >> 3);
  if (r >= NBX * NBY) return;
  const int bx = r / NBY, by = r - bx * NBY;
  const int m0 = bx * 128, n0 = by * 128;

  const int t = threadIdx.x;
  const int lane = t & 63, wid = t >> 6;
  const int wr = wid >> 1, wc = wid & 1;
  const int l15 = lane & 15, kg = lane >> 4;
  const int nk = K >> 5;

  const int srow = lane >> 2;
  const int koct = (lane & 3) ^ ((lane >> 3) & 3);
  const int rsw = (l15 >> 1) & 3;

  const size_t WA0 = (size_t)(n0 + wid * 16 + srow) * K + koct * 8;
  const size_t WA1 = WA0 + (size_t)64 * K;
  const size_t XB0 = (size_t)(m0 + wid * 16 + srow) * K + koct * 8;
  const size_t XB1 = XB0 + (size_t)64 * K;

  f4v acc[4][4];
#pragma unroll
  for (int i = 0; i < 4; ++i)
#pragma unroll
    for (int j = 0; j < 4; ++j) acc[i][j] = (f4v){0.f, 0.f, 0.f, 0.f};

#define STAGE(ks_)                                                       \
  { char* d_ = &lds[(ks_) % 3][0]; const int ko_ = (ks_) << 5;           \
    gload16(Wt + WA0 + ko_,  d_ + wid * 1024);                           \
    gload16(Wt + WA1 + ko_,  d_ + 4096 + wid * 1024);                    \
    gload16(Act + XB0 + ko_, d_ + 8192 + wid * 1024);                    \
    gload16(Act + XB1 + ko_, d_ + 12288 + wid * 1024); }

  STAGE(0);
  STAGE(1);

  for (int ks = 0; ks < nk; ++ks) {
    if (ks + 1 < nk) {
      asm volatile("s_waitcnt vmcnt(4)" ::: "memory");
    } else {
      asm volatile("s_waitcnt vmcnt(0)" ::: "memory");
    }
    __builtin_amdgcn_s_barrier();
    asm volatile("" ::: "memory");
    if (ks + 2 < nk) STAGE(ks + 2);

    const char* d = &lds[ks % 3][0];
    s8v av[4], bv[4];
#pragma unroll
    for (int mr = 0; mr < 4; ++mr)
      av[mr] = *(const s8v*)(d + (wr * 64 + mr * 16 + l15) * 64 + ((kg ^ rsw) << 4));
#pragma unroll
    for (int nr = 0; nr < 4; ++nr)
      bv[nr] = *(const s8v*)(d + 8192 + (wc * 64 + nr * 16 + l15) * 64 + ((kg ^ rsw) << 4));
#pragma unroll
    for (int mr = 0; mr < 4; ++mr)
#pragma unroll
      for (int nr = 0; nr < 4; ++nr)
        acc[mr][nr] = __builtin_amdgcn_mfma_f32_16x16x32_bf16(av[mr], bv[nr],
                                                              acc[mr][nr], 0, 0, 0);
  }
#undef STAGE

  // ---- coalesced 2-pass epilogue ----
  __syncthreads();   // K-loop LDS reads drained; lds[] now scratch
  char* scr = &lds[0][0] + wid * 8192;   // per-wave 8KB: [64 rows][32 ch fp32 = 128B]
#pragma unroll
  for (int p = 0; p < 2; ++p) {
#pragma unroll
    for (int m2 = 0; m2 < 2; ++m2) {
      const int mr = 2 * p + m2;
      const int ch = n0 + wr * 64 + mr * 16 + kg * 4;
      const float4 b4 = *(const float4*)(bias + ch);
      const int dbyte = m2 * 64 + kg * 16;
#pragma unroll
      for (int nr = 0; nr < 4; ++nr) {
        const int rl = nr * 16 + l15;
        float4 o;
        o.x = acc[mr][nr][0] + b4.x;
        o.y = acc[mr][nr][1] + b4.y;
        o.z = acc[mr][nr][2] + b4.z;
        o.w = acc[mr][nr][3] + b4.w;
        *(float4*)(scr + ((rl * 128 + dbyte) ^ ((rl & 7) << 4))) = o;
      }
    }
    const int cb = n0 + wr * 64 + p * 32;   // 32-ch base (fp32 -> 128B aligned)
    float* colbase = Cout + cb;
    const int r8 = lane >> 3, seg = (lane & 7) * 16;
#pragma unroll
    for (int j = 0; j < 8; ++j) {
      const int rl = j * 8 + r8;
      uint4 v = *(const uint4*)(scr + ((rl * 128 + seg) ^ ((rl & 7) << 4)));
      const int row = m0 + wc * 64 + rl;
      *(uint4*)((char*)(colbase + (size_t)row * N) + seg) = v;
    }
  }
}

// ---------------- fused softmax + bilinear sampling (R14-proven) ----------------
__global__ __launch_bounds__(256)
void deform_sample_k(const ushort_t* __restrict__ value,   // bf16 (N,H,LIN,64)
                     const float* __restrict__ oa,         // (N*LQ, 512): off|logit
                     const float* __restrict__ refp,       // (N*LQ, 3, 2)
                     uint_t* __restrict__ otmp) {          // bf16 pairs (N*LQ, 192)
  __shared__ int4 sp[4][56];
  const int lane = threadIdx.x & 63, wv = threadIdx.x >> 6;
  const int wid = blockIdx.x * 4 + wv;
  const int s = wid >> 11;          // slice 0..23
  const int qq = wid & 2047;
  const int nb = s / HH, h = s - nb * HH;
  const int nq = nb * LQ + qq;

  float lg = -INFINITY;
  if (lane < 27) lg = oa[(size_t)nq * NOA + 324 + h * 27 + lane];
  float mx = lg;
#pragma unroll
  for (int m = 1; m < 64; m <<= 1) mx = fmaxf(mx, __shfl_xor(mx, m, 64));
  float e = (lane < 27) ? __expf(lg - mx) : 0.f;
  float ssum = e;
#pragma unroll
  for (int m = 1; m < 64; m <<= 1) ssum += __shfl_xor(ssum, m, 64);

  if (lane < 27) {
    const float aw = e / ssum;
    const int lvl = (lane >= 18) ? 2 : (lane >= 9 ? 1 : 0);
    const float Wf = (lvl == 0) ? 112.f : (lvl == 1 ? 56.f : 28.f);
    const int Wi = (lvl == 0) ? 112 : (lvl == 1 ? 56 : 28);
    const int base = (lvl == 0) ? 0 : (lvl == 1 ? 12544 : 15680);
    const float2 rp = *(const float2*)(refp + (size_t)nq * 6 + lvl * 2);
    const float2 of = *(const float2*)(oa + (size_t)nq * NOA + h * 54 + lane * 2);
    const float x = rp.x * Wf + of.x - 0.5f;
    const float y = rp.y * Wf + of.y - 0.5f;
    const float x0f = floorf(x), y0f = floorf(y);
    const float wx1 = x - x0f, wy1 = y - y0f;
    const float wx0 = 1.f - wx1, wy0 = 1.f - wy1;
    const int x0 = (int)x0f, y0 = (int)y0f;
    const int x1 = x0 + 1, y1 = y0 + 1;
    const bool bx0 = (x0 >= 0) & (x0 < Wi), bx1 = (x1 >= 0) & (x1 < Wi);
    const bool by0 = (y0 >= 0) & (y0 < Wi), by1 = (y1 >= 0) & (y1 < Wi);
    const int a00 = (bx0 & by0) ? ((base + y0 * Wi + x0) << 7) : 0;
    const int a01 = (bx1 & by0) ? ((base + y0 * Wi + x1) << 7) : 0;
    const int a10 = (bx0 & by1) ? ((base + y1 * Wi + x0) << 7) : 0;
    const int a11 = (bx1 & by1) ? ((base + y1 * Wi + x1) << 7) : 0;
    const float w00 = (bx0 & by0) ? aw * wx0 * wy0 : 0.f;
    const float w01 = (bx1 & by0) ? aw * wx1 * wy0 : 0.f;
    const float w10 = (bx0 & by1) ? aw * wx0 * wy1 : 0.f;
    const float w11 = (bx1 & by1) ? aw * wx1 * wy1 : 0.f;
    sp[wv][lane * 2 + 0] = make_int4(a00, __float_as_int(w00), a01, __float_as_int(w01));
    sp[wv][lane * 2 + 1] = make_int4(a10, __float_as_int(w10), a11, __float_as_int(w11));
  } else if (lane == 27) {
    sp[wv][54] = make_int4(0, 0, 0, 0);
    sp[wv][55] = make_int4(0, 0, 0, 0);
  }
  __syncthreads();

  const uint_t slice = (uint_t)__builtin_amdgcn_readfirstlane(s);
  const char* vbase = (const char*)value + (size_t)slice * (LIN * DH * 2);
  const int j4 = (lane & 31) * 4;
  const int half = lane >> 5;
  float a0 = 0.f, a1 = 0.f;
  __builtin_amdgcn_s_setprio(1);
#pragma unroll
  for (int i = 0; i < 14; ++i) {
    const int pt = half * 14 + i;
    const int4 c01 = sp[wv][pt * 2];
    const int4 c23 = sp[wv][pt * 2 + 1];
    const uint_t u0 = *(const uint_t*)(vbase + (uint_t)(c01.x + j4));
    const uint_t u1 = *(const uint_t*)(vbase + (uint_t)(c01.z + j4));
    const uint_t u2 = *(const uint_t*)(vbase + (uint_t)(c23.x + j4));
    const uint_t u3 = *(const uint_t*)(vbase + (uint_t)(c23.z + j4));
    const float w0 = __int_as_float(c01.y), w1 = __int_as_float(c01.w);
    const float w2 = __int_as_float(c23.y), w3 = __int_as_float(c23.w);
    a0 += w0 * __uint_as_float(u0 << 16);
    a1 += w0 * __uint_as_float(u0 & 0xffff0000u);
    a0 += w1 * __uint_as_float(u1 << 16);
    a1 += w1 * __uint_as_float(u1 & 0xffff0000u);
    a0 += w2 * __uint_as_float(u2 << 16);
    a1 += w2 * __uint_as_float(u2 & 0xffff0000u);
    a0 += w3 * __uint_as_float(u3 << 16);
    a1 += w3 * __uint_as_float(u3 & 0xffff0000u);
  }
  __builtin_amdgcn_s_setprio(0);
  a0 += __shfl_xor(a0, 32, 64);
  a1 += __shfl_xor(a1, 32, 64);
  if (lane < 32) {
    const uint_t packed = (uint_t)f2bf(a0) | ((uint_t)f2bf(a1) << 16);
    otmp[(size_t)nq * 192 + h * 32 + lane] = packed;
  }
}

// ---------------- launch ----------------
extern "C" void kernel_launch(void* const* d_in, const int* in_sizes, int n_in,
                              void* d_out, int out_size, void* d_ws, size_t ws_size,
                              hipStream_t stream) {
  const float* tgt   = (const float*)d_in[0];
  const float* src   = (const float*)d_in[1];
  const float* qpos  = (const float*)d_in[2];
  const float* refp  = (const float*)d_in[3];
  const float* W_off  = (const float*)d_in[7];
  const float* b_off  = (const float*)d_in[8];
  const float* W_attn = (const float*)d_in[9];
  const float* b_attn = (const float*)d_in[10];
  const float* W_val  = (const float*)d_in[11];
  const float* b_val  = (const float*)d_in[12];
  const float* W_out  = (const float*)d_in[13];
  const float* b_out  = (const float*)d_in[14];

  char* ws = (char*)d_ws;
  ushort_t* val_bf  = (ushort_t*)(ws);              // 50,577,408 B
  float*    oa      = (float*)   (ws + 50577408);   // 16,777,216
  ushort_t* q_bf    = (ushort_t*)(ws + 67354624);   //  4,194,304
  uint_t*   otmp    = (uint_t*)  (ws + 71548928);   //  6,291,456
  ushort_t* bt_val  = (ushort_t*)(ws + 77840384);   //    196,608
  ushort_t* bt_oa   = (ushort_t*)(ws + 78036992);   //    262,144
  ushort_t* bt_out  = (ushort_t*)(ws + 78299136);   //    196,608
  float*    bias_oa = (float*)   (ws + 78495744);   //      2,048

  // fused prep: q add+cvt, weight transposes, bias concat (src handled in-GEMM)
  prep_k<<<3330, 256, 0, stream>>>((const float4*)tgt, (const float4*)qpos,
                                   (ushort4*)q_bf, W_val, bt_val,
                                   W_off, W_attn, bt_oa, W_out, bt_out,
                                   b_off, b_attn, bias_oa);

  // value = src(fp32) @ W_val + b_val -> bf16 permuted (N,H,LIN,64)
  mfma_gemm_vsrc_k<194><<<1552, 256, 0, stream>>>(src, bt_val, b_val, val_bf);
  // [off | logit] = q @ [W_off|W_attn] + bias (fp32, N=512): 64x4 tiles
  mfma_gemm_k<64, 4, 32><<<256, 256, 0, stream>>>(
      q_bf, bt_oa, bias_oa, oa, NOA, DM);

  // fused softmax + sampling -> otmp bf16
  deform_sample_k<<<12288, 256, 0, stream>>>(val_bf, oa, refp, otmp);

  // out = otmp @ W_out + b_out (fp32, final, K=384): 64x2 tiles
  mfma_gemm_k<64, 2, 16><<<128, 256, 0, stream>>>(
      (const ushort_t*)otmp, bt_out, b_out, (float*)d_out, DM, NVAL);
}

// Round 19
// 95.648 us; speedup vs baseline: 1.3147x; 1.0320x over previous
//
#include <hip/hip_runtime.h>
#include <math.h>

#define NB 4
#define LQ 2048
#define DM 256
#define HH 6
#define DH 64
#define LIN 16464
#define NOA 512             // fused off(324)+attn(162) padded
#define NVAL 384

typedef unsigned short ushort_t;
typedef unsigned int uint_t;
typedef __attribute__((ext_vector_type(8))) short s8v;   // 8 bf16 = 4 VGPR
typedef __attribute__((ext_vector_type(4))) float f4v;   // MFMA accumulator
typedef __attribute__((ext_vector_type(2))) float f2v;   // packed fma pair

__device__ __forceinline__ ushort_t f2bf(float f) {
  union { float f; unsigned u; } v; v.f = f;
  unsigned r = v.u + 0x7fffu + ((v.u >> 16) & 1u);  // RNE
  return (ushort_t)(r >> 16);
}

__device__ __forceinline__ uint_t cvtpk(float lo, float hi) {
  uint_t r;
  asm("v_cvt_pk_bf16_f32 %0, %1, %2" : "=v"(r) : "v"(lo), "v"(hi));
  return r;
}

typedef __attribute__((address_space(3))) char lds_char_t;
typedef const __attribute__((address_space(1))) char glb_char_t;
__device__ __forceinline__ void gload16(const void* g, void* l) {
  __builtin_amdgcn_global_load_lds((glb_char_t*)g, (lds_char_t*)l, 16, 0, 0);
}

// ---------------- fused prep: addq + weight transposes + bias ----------------
__global__ __launch_bounds__(256)
void prep_k(const float4* __restrict__ tgt, const float4* __restrict__ qpos,
            ushort4* __restrict__ q_bf,
            const float* __restrict__ W_val, ushort_t* __restrict__ bt_val,
            const float* __restrict__ W_off, const float* __restrict__ W_attn,
            ushort_t* __restrict__ bt_oa,
            const float* __restrict__ W_out, ushort_t* __restrict__ bt_out,
            const float* __restrict__ b_off, const float* __restrict__ b_attn,
            float* __restrict__ bias_oa) {
  const int blk = blockIdx.x, tid = threadIdx.x;
  if (blk < 2048) {
    const int i = blk * 256 + tid;
    float4 x = tgt[i], y = qpos[i];
    ushort4 r;
    r.x = f2bf(x.x + y.x); r.y = f2bf(x.y + y.y);
    r.z = f2bf(x.z + y.z); r.w = f2bf(x.w + y.w);
    q_bf[i] = r;
  } else {
    const int i = (blk - 2048) * 256 + tid;
    if (i < 98304) {              // bt_val[n][k] = W_val[k][n], 384x256
      const int n = i >> 8, k = i & 255;
      bt_val[i] = f2bf(W_val[(size_t)k * 384 + n]);
    } else if (i < 229376) {      // bt_oa: 512x256
      const int j = i - 98304;
      const int n = j >> 8, k = j & 255;
      float v = 0.f;
      if (n < 324) v = W_off[(size_t)k * 324 + n];
      else if (n < 486) v = W_attn[(size_t)k * 162 + (n - 324)];
      bt_oa[j] = f2bf(v);
    } else if (i < 327680) {      // bt_out: 256x384
      const int j = i - 229376;
      const int n = j / 384, k = j - n * 384;
      bt_out[j] = f2bf(W_out[(size_t)k * 256 + n]);
    } else {                      // bias_oa 512
      const int j = i - 327680;
      if (j < 512) bias_oa[j] = (j < 324) ? b_off[j] : (j < 486 ? b_attn[j - 324] : 0.f);
    }
  }
}

// ------------- value GEMM (R17-proven): R11 K-loop + coalesced LDS-transpose epilogue ----
template <int CPX>
__global__ __launch_bounds__(256)
void mfma_gemm_vsrc_k(const float* __restrict__ Src, const ushort_t* __restrict__ Wt,
                      const float* __restrict__ bias, ushort_t* __restrict__ Cout) {
  __shared__ char lds[3][16384];
  const int bid = blockIdx.x;
  const int r = (bid & 7) * CPX + (bid >> 3);
  if (r >= 1548) return;
  const int bx = r / 3, by = r - bx * 3;
  const int bq = bx / 129;                 // batch
  const int rb = (bx - bq * 129) * 128;    // row base within batch
  const int n0 = by * 128;                 // channels

  const int t = threadIdx.x;
  const int lane = t & 63, wid = t >> 6;
  const int wr = wid >> 1, wc = wid & 1;
  const int l15 = lane & 15, kg = lane >> 4;

  const int srow = lane >> 2;
  const int koct = (lane & 3) ^ ((lane >> 3) & 3);
  const int rsw = (l15 >> 1) & 3;
  const size_t WS0 = (size_t)(n0 + wid * 16 + srow) * DM + koct * 8;
  const size_t WS1 = WS0 + (size_t)64 * DM;

  const int ar = t >> 2, sA = t & 3;
  const int oA = sA ^ (((ar & 15) >> 1) & 3);
  const int rA0 = rb + ar, rA1 = rb + ar + 64;
  const float* pa = Src + ((size_t)bq * LIN + (rA0 < LIN ? rA0 : LIN - 1)) * DM + oA * 8;
  const float* pb = Src + ((size_t)bq * LIN + (rA1 < LIN ? rA1 : LIN - 1)) * DM + oA * 8;

  f4v acc[4][4];
#pragma unroll
  for (int i = 0; i < 4; ++i)
#pragma unroll
    for (int j = 0; j < 4; ++j) acc[i][j] = (f4v){0.f, 0.f, 0.f, 0.f};

  float4 lA[4], lB[4];

#define AL(dst_, g_)                                                     \
  { const int kb_ = (g_) << 5;                                           \
    dst_[0] = *(const float4*)(pa + kb_);                                \
    dst_[1] = *(const float4*)(pa + kb_ + 4);                            \
    dst_[2] = *(const float4*)(pb + kb_);                                \
    dst_[3] = *(const float4*)(pb + kb_ + 4); }

#define AW(src_, g_)                                                    \
  { char* d_ = &lds[(g_) % 3][8192] + t * 16;                           \
    uint4 c0, c1;                                                       \
    c0.x = cvtpk(src_[0].x, src_[0].y); c0.y = cvtpk(src_[0].z, src_[0].w); \
    c0.z = cvtpk(src_[1].x, src_[1].y); c0.w = cvtpk(src_[1].z, src_[1].w); \
    c1.x = cvtpk(src_[2].x, src_[2].y); c1.y = cvtpk(src_[2].z, src_[2].w); \
    c1.z = cvtpk(src_[3].x, src_[3].y); c1.w = cvtpk(src_[3].z, src_[3].w); \
    *(uint4*)(d_) = c0;                                                 \
    *(uint4*)(d_ + 4096) = c1; }

#define GW(g_)                                                          \
  { char* d_ = &lds[(g_) % 3][0]; const int ko_ = (g_) << 5;            \
    gload16(Wt + WS0 + ko_, d_ + wid * 1024);                           \
    gload16(Wt + WS1 + ko_, d_ + 4096 + wid * 1024); }

  AL(lA, 0);
  GW(0);
  asm volatile("s_waitcnt vmcnt(2)" ::: "memory");
  AW(lA, 0);
  AL(lA, 1);
  GW(1);
  asm volatile("s_waitcnt vmcnt(2)" ::: "memory");
  AW(lA, 1);
  AL(lA, 2);

#pragma unroll
  for (int gs = 0; gs < 8; ++gs) {
    if (gs <= 4) {
      if (gs & 1) { AL(lA, gs + 3); } else { AL(lB, gs + 3); }
    }
    if (gs == 7) asm volatile("s_waitcnt vmcnt(0)" ::: "memory");
    asm volatile("s_waitcnt lgkmcnt(0)" ::: "memory");
    __builtin_amdgcn_s_barrier();
    asm volatile("" ::: "memory");
    if (gs <= 5) GW(gs + 2);

    const char* d = &lds[gs % 3][0];
    s8v av[4], bv[4];
#pragma unroll
    for (int mr = 0; mr < 4; ++mr)
      av[mr] = *(const s8v*)(d + (wr * 64 + mr * 16 + l15) * 64 + ((kg ^ rsw) << 4));
#pragma unroll
    for (int nr = 0; nr < 4; ++nr)
      bv[nr] = *(const s8v*)(d + 8192 + (wc * 64 + nr * 16 + l15) * 64 + ((kg ^ rsw) << 4));
#pragma unroll
    for (int mr = 0; mr < 4; ++mr)
#pragma unroll
      for (int nr = 0; nr < 4; ++nr)
        acc[mr][nr] = __builtin_amdgcn_mfma_f32_16x16x32_bf16(av[mr], bv[nr],
                                                              acc[mr][nr], 0, 0, 0);

    if (gs <= 5) {
      if (gs <= 4) {
        asm volatile("s_waitcnt vmcnt(6)" ::: "memory");
      } else {
        asm volatile("s_waitcnt vmcnt(2)" ::: "memory");
      }
      if (gs & 1) { AW(lB, gs + 2); } else { AW(lA, gs + 2); }
    }
  }
#undef AL
#undef AW
#undef GW

  // ---- coalesced epilogue (R17-proven) ----
  __syncthreads();   // all K-loop LDS reads drained; lds[] now free scratch
  char* scr = &lds[0][0] + wid * 8192;   // per-wave 8KB: [64 rows][128B d-range]
#pragma unroll
  for (int mr = 0; mr < 4; ++mr) {
    const int ch = n0 + wr * 64 + mr * 16 + kg * 4;
    const float4 b4 = *(const float4*)(bias + ch);
    const int dbyte = (mr * 16 + kg * 4) * 2;
#pragma unroll
    for (int nr = 0; nr < 4; ++nr) {
      const int rl = nr * 16 + l15;
      ushort4 o;
      o.x = f2bf(acc[mr][nr][0] + b4.x);
      o.y = f2bf(acc[mr][nr][1] + b4.y);
      o.z = f2bf(acc[mr][nr][2] + b4.z);
      o.w = f2bf(acc[mr][nr][3] + b4.w);
      *(ushort4*)(scr + ((rl * 128 + dbyte) ^ ((rl & 7) << 4))) = o;
    }
  }
  const int h = (n0 + wr * 64) >> 6;       // wave's single h-slice (64-aligned)
  ushort_t* slice_base = Cout + (size_t)(bq * HH + h) * LIN * DH;
  const int row0 = rb + wc * 64;
  const int r8 = lane >> 3, seg = (lane & 7) * 16;
#pragma unroll
  for (int j = 0; j < 8; ++j) {
    const int rl = j * 8 + r8;
    uint4 v = *(const uint4*)(scr + ((rl * 128 + seg) ^ ((rl & 7) << 4)));
    const int ii = row0 + rl;
    if (ii < LIN)
      *(uint4*)((char*)(slice_base + (size_t)ii * DH) + seg) = v;
  }
}

// ------------- bf16 MFMA GEMM (R7 K-loop) + coalesced 2-pass fp32 epilogue -------------
template <int NBX, int NBY, int CPX>
__global__ __launch_bounds__(256)
void mfma_gemm_k(const ushort_t* __restrict__ Act, const ushort_t* __restrict__ Wt,
                 const float* __restrict__ bias, float* __restrict__ Cout,
                 int N, int K) {
  __shared__ char lds[3][16384];
  const int bid = blockIdx.x;
  const int r = (bid & 7) * CPX + (bid >> 3);
  if (r >= NBX * NBY) return;
  const int bx = r / NBY, by = r - bx * NBY;
  const int m0 = bx * 128, n0 = by * 128;

  const int t = threadIdx.x;
  const int lane = t & 63, wid = t >> 6;
  const int wr = wid >> 1, wc = wid & 1;
  const int l15 = lane & 15, kg = lane >> 4;
  const int nk = K >> 5;

  const int srow = lane >> 2;
  const int koct = (lane & 3) ^ ((lane >> 3) & 3);
  const int rsw = (l15 >> 1) & 3;

  const size_t WA0 = (size_t)(n0 + wid * 16 + srow) * K + koct * 8;
  const size_t WA1 = WA0 + (size_t)64 * K;
  const size_t XB0 = (size_t)(m0 + wid * 16 + srow) * K + koct * 8;
  const size_t XB1 = XB0 + (size_t)64 * K;

  f4v acc[4][4];
#pragma unroll
  for (int i = 0; i < 4; ++i)
#pragma unroll
    for (int j = 0; j < 4; ++j) acc[i][j] = (f4v){0.f, 0.f, 0.f, 0.f};

#define STAGE(ks_)                                                       \
  { char* d_ = &lds[(ks_) % 3][0]; const int ko_ = (ks_) << 5;           \
    gload16(Wt + WA0 + ko_,  d_ + wid * 1024);                           \
    gload16(Wt + WA1 + ko_,  d_ + 4096 + wid * 1024);                    \
    gload16(Act + XB0 + ko_, d_ + 8192 + wid * 1024);                    \
    gload16(Act + XB1 + ko_, d_ + 12288 + wid * 1024); }

  STAGE(0);
  STAGE(1);

  for (int ks = 0; ks < nk; ++ks) {
    if (ks + 1 < nk) {
      asm volatile("s_waitcnt vmcnt(4)" ::: "memory");
    } else {
      asm volatile("s_waitcnt vmcnt(0)" ::: "memory");
    }
    __builtin_amdgcn_s_barrier();
    asm volatile("" ::: "memory");
    if (ks + 2 < nk) STAGE(ks + 2);

    const char* d = &lds[ks % 3][0];
    s8v av[4], bv[4];
#pragma unroll
    for (int mr = 0; mr < 4; ++mr)
      av[mr] = *(const s8v*)(d + (wr * 64 + mr * 16 + l15) * 64 + ((kg ^ rsw) << 4));
#pragma unroll
    for (int nr = 0; nr < 4; ++nr)
      bv[nr] = *(const s8v*)(d + 8192 + (wc * 64 + nr * 16 + l15) * 64 + ((kg ^ rsw) << 4));
#pragma unroll
    for (int mr = 0; mr < 4; ++mr)
#pragma unroll
      for (int nr = 0; nr < 4; ++nr)
        acc[mr][nr] = __builtin_amdgcn_mfma_f32_16x16x32_bf16(av[mr], bv[nr],
                                                              acc[mr][nr], 0, 0, 0);
  }
#undef STAGE

  // ---- coalesced 2-pass epilogue (R18-proven) ----
  __syncthreads();   // K-loop LDS reads drained; lds[] now scratch
  char* scr = &lds[0][0] + wid * 8192;   // per-wave 8KB: [64 rows][32 ch fp32 = 128B]
#pragma unroll
  for (int p = 0; p < 2; ++p) {
#pragma unroll
    for (int m2 = 0; m2 < 2; ++m2) {
      const int mr = 2 * p + m2;
      const int ch = n0 + wr * 64 + mr * 16 + kg * 4;
      const float4 b4 = *(const float4*)(bias + ch);
      const int dbyte = m2 * 64 + kg * 16;
#pragma unroll
      for (int nr = 0; nr < 4; ++nr) {
        const int rl = nr * 16 + l15;
        float4 o;
        o.x = acc[mr][nr][0] + b4.x;
        o.y = acc[mr][nr][1] + b4.y;
        o.z = acc[mr][nr][2] + b4.z;
        o.w = acc[mr][nr][3] + b4.w;
        *(float4*)(scr + ((rl * 128 + dbyte) ^ ((rl & 7) << 4))) = o;
      }
    }
    const int cb = n0 + wr * 64 + p * 32;   // 32-ch base (fp32 -> 128B aligned)
    float* colbase = Cout + cb;
    const int r8 = lane >> 3, seg = (lane & 7) * 16;
#pragma unroll
    for (int j = 0; j < 8; ++j) {
      const int rl = j * 8 + r8;
      uint4 v = *(const uint4*)(scr + ((rl * 128 + seg) ^ ((rl & 7) << 4)));
      const int row = m0 + wc * 64 + rl;
      *(uint4*)((char*)(colbase + (size_t)row * N) + seg) = v;
    }
  }
}

// ---------------- fused softmax + bilinear sampling: packed f2v accumulate ----------------
__global__ __launch_bounds__(256)
void deform_sample_k(const ushort_t* __restrict__ value,   // bf16 (N,H,LIN,64)
                     const float* __restrict__ oa,         // (N*LQ, 512): off|logit
                     const float* __restrict__ refp,       // (N*LQ, 3, 2)
                     uint_t* __restrict__ otmp) {          // bf16 pairs (N*LQ, 192)
  __shared__ int4 sp[4][56];
  const int lane = threadIdx.x & 63, wv = threadIdx.x >> 6;
  const int wid = blockIdx.x * 4 + wv;
  const int s = wid >> 11;          // slice 0..23
  const int qq = wid & 2047;
  const int nb = s / HH, h = s - nb * HH;
  const int nq = nb * LQ + qq;

  float lg = -INFINITY;
  if (lane < 27) lg = oa[(size_t)nq * NOA + 324 + h * 27 + lane];
  float mx = lg;
#pragma unroll
  for (int m = 1; m < 64; m <<= 1) mx = fmaxf(mx, __shfl_xor(mx, m, 64));
  float e = (lane < 27) ? __expf(lg - mx) : 0.f;
  float ssum = e;
#pragma unroll
  for (int m = 1; m < 64; m <<= 1) ssum += __shfl_xor(ssum, m, 64);

  if (lane < 27) {
    const float aw = e / ssum;
    const int lvl = (lane >= 18) ? 2 : (lane >= 9 ? 1 : 0);
    const float Wf = (lvl == 0) ? 112.f : (lvl == 1 ? 56.f : 28.f);
    const int Wi = (lvl == 0) ? 112 : (lvl == 1 ? 56 : 28);
    const int base = (lvl == 0) ? 0 : (lvl == 1 ? 12544 : 15680);
    const float2 rp = *(const float2*)(refp + (size_t)nq * 6 + lvl * 2);
    const float2 of = *(const float2*)(oa + (size_t)nq * NOA + h * 54 + lane * 2);
    const float x = rp.x * Wf + of.x - 0.5f;
    const float y = rp.y * Wf + of.y - 0.5f;
    const float x0f = floorf(x), y0f = floorf(y);
    const float wx1 = x - x0f, wy1 = y - y0f;
    const float wx0 = 1.f - wx1, wy0 = 1.f - wy1;
    const int x0 = (int)x0f, y0 = (int)y0f;
    const int x1 = x0 + 1, y1 = y0 + 1;
    const bool bx0 = (x0 >= 0) & (x0 < Wi), bx1 = (x1 >= 0) & (x1 < Wi);
    const bool by0 = (y0 >= 0) & (y0 < Wi), by1 = (y1 >= 0) & (y1 < Wi);
    const int a00 = (bx0 & by0) ? ((base + y0 * Wi + x0) << 7) : 0;
    const int a01 = (bx1 & by0) ? ((base + y0 * Wi + x1) << 7) : 0;
    const int a10 = (bx0 & by1) ? ((base + y1 * Wi + x0) << 7) : 0;
    const int a11 = (bx1 & by1) ? ((base + y1 * Wi + x1) << 7) : 0;
    const float w00 = (bx0 & by0) ? aw * wx0 * wy0 : 0.f;
    const float w01 = (bx1 & by0) ? aw * wx1 * wy0 : 0.f;
    const float w10 = (bx0 & by1) ? aw * wx0 * wy1 : 0.f;
    const float w11 = (bx1 & by1) ? aw * wx1 * wy1 : 0.f;
    sp[wv][lane * 2 + 0] = make_int4(a00, __float_as_int(w00), a01, __float_as_int(w01));
    sp[wv][lane * 2 + 1] = make_int4(a10, __float_as_int(w10), a11, __float_as_int(w11));
  } else if (lane == 27) {
    sp[wv][54] = make_int4(0, 0, 0, 0);
    sp[wv][55] = make_int4(0, 0, 0, 0);
  }
  __syncthreads();

  const uint_t slice = (uint_t)__builtin_amdgcn_readfirstlane(s);
  const char* vbase = (const char*)value + (size_t)slice * (LIN * DH * 2);
  const int j4 = (lane & 31) * 4;
  const int half = lane >> 5;
  f2v acc2 = (f2v){0.f, 0.f};
  __builtin_amdgcn_s_setprio(1);
#pragma unroll
  for (int i = 0; i < 14; ++i) {
    const int pt = half * 14 + i;
    const int4 c01 = sp[wv][pt * 2];
    const int4 c23 = sp[wv][pt * 2 + 1];
    const uint_t u0 = *(const uint_t*)(vbase + (uint_t)(c01.x + j4));
    const uint_t u1 = *(const uint_t*)(vbase + (uint_t)(c01.z + j4));
    const uint_t u2 = *(const uint_t*)(vbase + (uint_t)(c23.x + j4));
    const uint_t u3 = *(const uint_t*)(vbase + (uint_t)(c23.z + j4));
    const float w0 = __int_as_float(c01.y), w1 = __int_as_float(c01.w);
    const float w2 = __int_as_float(c23.y), w3 = __int_as_float(c23.w);
#define PKACC(u_, w_)                                                    \
    {                                                                    \
      f2v v_;                                                            \
      v_[0] = __uint_as_float((u_) << 16);                               \
      v_[1] = __uint_as_float((u_) & 0xffff0000u);                       \
      acc2 += (f2v){(w_), (w_)} * v_;                                    \
    }
    PKACC(u0, w0);
    PKACC(u1, w1);
    PKACC(u2, w2);
    PKACC(u3, w3);
#undef PKACC
  }
  __builtin_amdgcn_s_setprio(0);
  float a0 = acc2[0], a1 = acc2[1];
  a0 += __shfl_xor(a0, 32, 64);
  a1 += __shfl_xor(a1, 32, 64);
  if (lane < 32) {
    const uint_t packed = (uint_t)f2bf(a0) | ((uint_t)f2bf(a1) << 16);
    otmp[(size_t)nq * 192 + h * 32 + lane] = packed;
  }
}

// ---------------- launch ----------------
extern "C" void kernel_launch(void* const* d_in, const int* in_sizes, int n_in,
                              void* d_out, int out_size, void* d_ws, size_t ws_size,
                              hipStream_t stream) {
  const float* tgt   = (const float*)d_in[0];
  const float* src   = (const float*)d_in[1];
  const float* qpos  = (const float*)d_in[2];
  const float* refp  = (const float*)d_in[3];
  const float* W_off  = (const float*)d_in[7];
  const float* b_off  = (const float*)d_in[8];
  const float* W_attn = (const float*)d_in[9];
  const float* b_attn = (const float*)d_in[10];
  const float* W_val  = (const float*)d_in[11];
  const float* b_val  = (const float*)d_in[12];
  const float* W_out  = (const float*)d_in[13];
  const float* b_out  = (const float*)d_in[14];

  char* ws = (char*)d_ws;
  ushort_t* val_bf  = (ushort_t*)(ws);              // 50,577,408 B
  float*    oa      = (float*)   (ws + 50577408);   // 16,777,216
  ushort_t* q_bf    = (ushort_t*)(ws + 67354624);   //  4,194,304
  uint_t*   otmp    = (uint_t*)  (ws + 71548928);   //  6,291,456
  ushort_t* bt_val  = (ushort_t*)(ws + 77840384);   //    196,608
  ushort_t* bt_oa   = (ushort_t*)(ws + 78036992);   //    262,144
  ushort_t* bt_out  = (ushort_t*)(ws + 78299136);   //    196,608
  float*    bias_oa = (float*)   (ws + 78495744);   //      2,048

  // fused prep: q add+cvt, weight transposes, bias concat (src handled in-GEMM)
  prep_k<<<3330, 256, 0, stream>>>((const float4*)tgt, (const float4*)qpos,
                                   (ushort4*)q_bf, W_val, bt_val,
                                   W_off, W_attn, bt_oa, W_out, bt_out,
                                   b_off, b_attn, bias_oa);

  // value = src(fp32) @ W_val + b_val -> bf16 permuted (N,H,LIN,64)
  mfma_gemm_vsrc_k<194><<<1552, 256, 0, stream>>>(src, bt_val, b_val, val_bf);
  // [off | logit] = q @ [W_off|W_attn] + bias (fp32, N=512): 64x4 tiles
  mfma_gemm_k<64, 4, 32><<<256, 256, 0, stream>>>(
      q_bf, bt_oa, bias_oa, oa, NOA, DM);

  // fused softmax + sampling -> otmp bf16
  deform_sample_k<<<12288, 256, 0, stream>>>(val_bf, oa, refp, otmp);

  // out = otmp @ W_out + b_out (fp32, final, K=384): 64x2 tiles
  mfma_gemm_k<64, 2, 16><<<128, 256, 0, stream>>>(
      (const ushort_t*)otmp, bt_out, b_out, (float*)d_out, DM, NVAL);
}